// Round 8
// baseline (432.614 us; speedup 1.0000x reference)
//
#include <hip/hip_runtime.h>
#include <hip/hip_bf16.h>

#define NN 100000
#define NE 1600000
#define DIN 128
#define NG 512
#define MAXD 64
#define NBUK 391               // dst>>8 buckets (256 nodes each)
#define BCAP 5120              // mean 4092, +16 sigma
#define CHUNK ((NE + NBUK - 1) / NBUK)
#define NTILE ((NN + 63) >> 6)  // 64-node tiles

typedef __attribute__((ext_vector_type(8))) __bf16 bf16x8;
typedef __attribute__((ext_vector_type(4))) float f32x4;

static __device__ __forceinline__ unsigned short bfhi(float f) {
    __hip_bfloat16 h = __float2bfloat16(f);
    return *reinterpret_cast<unsigned short*>(&h);
}
static __device__ __forceinline__ float bf2f(unsigned short u) {
    unsigned v = (unsigned)u << 16;
    return __uint_as_float(v);
}
static __device__ __forceinline__ bf16x8 ldfrag(const void* p) {
    bf16x8 r;
    __builtin_memcpy(&r, p, 16);
    return r;
}
// LDS frag-bank swizzle: XOR bits>=4 only (8B writes / 16B reads stay aligned).
static __device__ __forceinline__ int swz(int a) {
    return a ^ (((a >> 8) & 3) << 5) ^ (((a >> 12) & 3) << 4);
}

// Fragment addressing (mfma_f32_16x16x32_bf16):
//  A: lane l holds A[R0 + (l&15)][32*ks + 8*(l>>4) + j], j=0..7
//  B: lane l holds B[32*ks + 8*(l>>4) + j][C0 + (l&15)]
//  C/D: col = C0 + (lane&15), row = R0 + (lane>>4)*4 + reg   [verified layout]
// LDS frag order: byte = swz( (((slot*64 + lane)*8 + j) * 2) ), slot = ks*4 + rb/cb.

// ============ fused: phase-1 binning (blocks 0..NBUK) || input GEMM (rest) ============
#define GB 512
__global__ void __launch_bounds__(512) k_front(const int* __restrict__ src,
                                               const int* __restrict__ dst,
                                               int* __restrict__ cursor,
                                               unsigned int* __restrict__ bucket,
                                               const float* __restrict__ x,
                                               const float* __restrict__ W0,
                                               const float* __restrict__ b0,
                                               float* __restrict__ h) {
    __shared__ unsigned short sS[2 * 8192];   // 2 planes x 16 KB (W0 prepack, then x tiles)
    __shared__ int lcnt[NBUK];
    __shared__ int lbase[NBUK];
    if (blockIdx.x < NBUK) {
        for (int i = threadIdx.x; i < NBUK; i += 512) lcnt[i] = 0;
        __syncthreads();
        int e0 = blockIdx.x * CHUNK;
        int e1 = min(e0 + CHUNK, NE);
        for (int e = e0 + (int)threadIdx.x; e < e1; e += 512)
            atomicAdd(&lcnt[dst[e] >> 8], 1);
        __syncthreads();
        for (int i = threadIdx.x; i < NBUK; i += 512) {
            int c = lcnt[i];
            lbase[i] = c ? atomicAdd(&cursor[i], c) : 0;
            lcnt[i] = 0;
        }
        __syncthreads();
        for (int e = e0 + (int)threadIdx.x; e < e1; e += 512) {
            int d = dst[e];
            int s = src[e];
            int bk = d >> 8;
            int pos = lbase[bk] + atomicAdd(&lcnt[bk], 1);
            if (pos < BCAP)
                bucket[(size_t)bk * BCAP + pos] = ((unsigned)s << 8) | (unsigned)(d & 255);
        }
    } else {
        // ---- input GEMM via MFMA bf16x3: h = relu(x @ W0 + b0) ----
        unsigned short* sP0 = sS;
        unsigned short* sP1 = sS + 8192;
        for (int i = threadIdx.x; i < 8192; i += 512) {
            int k = i >> 6, c = i & 63;
            int slot = ((k >> 5) << 2) | (c >> 4);
            int ln   = (((k >> 3) & 3) << 4) | (c & 15);
            int ba   = swz((((((slot << 6) | ln) << 3) | (k & 7)) << 1));
            float w0 = W0[i];
            unsigned short hh = bfhi(w0);
            *(unsigned short*)((char*)sP0 + ba) = hh;
            *(unsigned short*)((char*)sP1 + ba) = bfhi(w0 - bf2f(hh));
        }
        __syncthreads();
        int lane = threadIdx.x & 63;
        int wv   = threadIdx.x >> 6;
        int cb   = wv & 3;
        int rbh  = wv >> 2;
        int col  = (cb << 4) | (lane & 15);
        float bj = b0[col];
        int r0   = (lane >> 4) << 2;
        bf16x8 Bh[4], Bl[4];
#pragma unroll
        for (int ks = 0; ks < 4; ++ks) {
            int bb = swz(((((ks << 2) | cb) << 6) | lane) << 4);
            Bh[ks] = ldfrag((const char*)sP0 + bb);
            Bl[ks] = ldfrag((const char*)sP1 + bb);
        }
        for (int t = blockIdx.x - NBUK; t < NTILE; t += GB) {
            int n0 = t << 6;
            __syncthreads();
#pragma unroll
            for (int i = 0; i < 4; ++i) {
                int tau = (int)threadIdx.x + (i << 9);
                int r = tau >> 5, kq = tau & 31;
                int n = n0 + r;
                float4 v = make_float4(0.f, 0.f, 0.f, 0.f);
                if (n < NN) v = *(const float4*)(x + ((size_t)n << 7) + (kq << 2));
                int k0   = kq << 2;
                int slot = ((k0 >> 5) << 2) | (r >> 4);
                int ln   = (((k0 >> 3) & 3) << 4) | (r & 15);
                int ba   = swz((((((slot << 6) | ln) << 3) | (k0 & 7)) << 1));
                unsigned short h0 = bfhi(v.x), h1 = bfhi(v.y),
                               h2 = bfhi(v.z), h3 = bfhi(v.w);
                *(ushort4*)((char*)sP0 + ba) = make_ushort4(h0, h1, h2, h3);
                *(ushort4*)((char*)sP1 + ba) = make_ushort4(
                    bfhi(v.x - bf2f(h0)), bfhi(v.y - bf2f(h1)),
                    bfhi(v.z - bf2f(h2)), bfhi(v.w - bf2f(h3)));
            }
            __syncthreads();
            f32x4 acc[2] = {{0.f,0.f,0.f,0.f},{0.f,0.f,0.f,0.f}};
#pragma unroll
            for (int ks = 0; ks < 4; ++ks) {
#pragma unroll
                for (int rl = 0; rl < 2; ++rl) {
                    int rb = (rbh << 1) | rl;
                    int ab = swz(((((ks << 2) | rb) << 6) | lane) << 4);
                    bf16x8 ah = ldfrag((const char*)sP0 + ab);
                    bf16x8 al = ldfrag((const char*)sP1 + ab);
                    acc[rl] = __builtin_amdgcn_mfma_f32_16x16x32_bf16(ah, Bh[ks], acc[rl], 0, 0, 0);
                    acc[rl] = __builtin_amdgcn_mfma_f32_16x16x32_bf16(ah, Bl[ks], acc[rl], 0, 0, 0);
                    acc[rl] = __builtin_amdgcn_mfma_f32_16x16x32_bf16(al, Bh[ks], acc[rl], 0, 0, 0);
                }
            }
#pragma unroll
            for (int rl = 0; rl < 2; ++rl) {
                int rb = (rbh << 1) | rl;
#pragma unroll
                for (int reg = 0; reg < 4; ++reg) {
                    int row = (rb << 4) + r0 + reg;
                    int n = n0 + row;
                    if (n < NN)
                        h[((size_t)n << 6) + col] = fmaxf(acc[rl][reg] + bj, 0.f);
                }
            }
        }
    }
}

// ---- gemmLR via MFMA bf16x3 (4-wave body, used by k_mid layer 0) ----
__device__ __forceinline__ void gemmLR_mfma(unsigned short* sS,
                                            int tid, int nblk, int bidx,
                                            float* __restrict__ h_r,
                                            __hip_bfloat16* __restrict__ g,
                                            const float* __restrict__ Wl,
                                            const float* __restrict__ bl,
                                            const float* __restrict__ Wr) {
    unsigned short* sP0 = sS;
    unsigned short* sP1 = sS + 4096;
    int lane = tid & 63;
    int cb   = tid >> 6;
    bf16x8 BLh[2], BLl[2], BRh[2], BRl[2];
    for (int i = tid; i < 4096; i += 256) {
        int k = i >> 6, c = i & 63;
        int slot = ((k >> 5) << 2) | (c >> 4);
        int ln   = (((k >> 3) & 3) << 4) | (c & 15);
        int ba   = swz((((((slot << 6) | ln) << 3) | (k & 7)) << 1));
        float w = Wl[i];
        unsigned short hh = bfhi(w);
        *(unsigned short*)((char*)sP0 + ba) = hh;
        *(unsigned short*)((char*)sP1 + ba) = bfhi(w - bf2f(hh));
    }
    __syncthreads();
#pragma unroll
    for (int ks = 0; ks < 2; ++ks) {
        int bb = swz(((((ks << 2) | cb) << 6) | lane) << 4);
        BLh[ks] = ldfrag((const char*)sP0 + bb);
        BLl[ks] = ldfrag((const char*)sP1 + bb);
    }
    __syncthreads();
    for (int i = tid; i < 4096; i += 256) {
        int k = i >> 6, c = i & 63;
        int slot = ((k >> 5) << 2) | (c >> 4);
        int ln   = (((k >> 3) & 3) << 4) | (c & 15);
        int ba   = swz((((((slot << 6) | ln) << 3) | (k & 7)) << 1));
        float w = Wr[i];
        unsigned short hh = bfhi(w);
        *(unsigned short*)((char*)sP0 + ba) = hh;
        *(unsigned short*)((char*)sP1 + ba) = bfhi(w - bf2f(hh));
    }
    __syncthreads();
#pragma unroll
    for (int ks = 0; ks < 2; ++ks) {
        int bb = swz(((((ks << 2) | cb) << 6) | lane) << 4);
        BRh[ks] = ldfrag((const char*)sP0 + bb);
        BRl[ks] = ldfrag((const char*)sP1 + bb);
    }
    int col = (cb << 4) | (lane & 15);
    float bj = bl[col];
    int r0  = (lane >> 4) << 2;
    unsigned short* gp = (unsigned short*)g;
    for (int t = bidx; t < NTILE; t += nblk) {
        int n0 = t << 6;
        __syncthreads();
#pragma unroll
        for (int i = 0; i < 4; ++i) {
            int tau = tid + (i << 8);
            int r = tau >> 4, kq = tau & 15;
            int n = n0 + r;
            float4 v = make_float4(0.f, 0.f, 0.f, 0.f);
            if (n < NN) v = *(const float4*)(h_r + ((size_t)n << 6) + (kq << 2));
            int k0   = kq << 2;
            int slot = ((k0 >> 5) << 2) | (r >> 4);
            int ln   = (((k0 >> 3) & 3) << 4) | (r & 15);
            int ba   = swz((((((slot << 6) | ln) << 3) | (k0 & 7)) << 1));
            unsigned short h0 = bfhi(v.x), h1 = bfhi(v.y),
                           h2 = bfhi(v.z), h3 = bfhi(v.w);
            *(ushort4*)((char*)sP0 + ba) = make_ushort4(h0, h1, h2, h3);
            *(ushort4*)((char*)sP1 + ba) = make_ushort4(
                bfhi(v.x - bf2f(h0)), bfhi(v.y - bf2f(h1)),
                bfhi(v.z - bf2f(h2)), bfhi(v.w - bf2f(h3)));
        }
        __syncthreads();
        f32x4 accl[4] = {{0.f,0.f,0.f,0.f},{0.f,0.f,0.f,0.f},
                         {0.f,0.f,0.f,0.f},{0.f,0.f,0.f,0.f}};
        f32x4 accr[4] = {{0.f,0.f,0.f,0.f},{0.f,0.f,0.f,0.f},
                         {0.f,0.f,0.f,0.f},{0.f,0.f,0.f,0.f}};
#pragma unroll
        for (int ks = 0; ks < 2; ++ks) {
#pragma unroll
            for (int rb = 0; rb < 4; ++rb) {
                int ab = swz(((((ks << 2) | rb) << 6) | lane) << 4);
                bf16x8 ah = ldfrag((const char*)sP0 + ab);
                bf16x8 al = ldfrag((const char*)sP1 + ab);
                accl[rb] = __builtin_amdgcn_mfma_f32_16x16x32_bf16(ah, BLh[ks], accl[rb], 0, 0, 0);
                accl[rb] = __builtin_amdgcn_mfma_f32_16x16x32_bf16(ah, BLl[ks], accl[rb], 0, 0, 0);
                accl[rb] = __builtin_amdgcn_mfma_f32_16x16x32_bf16(al, BLh[ks], accl[rb], 0, 0, 0);
                accr[rb] = __builtin_amdgcn_mfma_f32_16x16x32_bf16(ah, BRh[ks], accr[rb], 0, 0, 0);
                accr[rb] = __builtin_amdgcn_mfma_f32_16x16x32_bf16(ah, BRl[ks], accr[rb], 0, 0, 0);
                accr[rb] = __builtin_amdgcn_mfma_f32_16x16x32_bf16(al, BRh[ks], accr[rb], 0, 0, 0);
            }
        }
#pragma unroll
        for (int rb = 0; rb < 4; ++rb) {
#pragma unroll
            for (int reg = 0; reg < 4; ++reg) {
                int row = (rb << 4) + r0 + reg;
                int n = n0 + row;
                if (n < NN) {
                    size_t o = ((size_t)n << 6) + col;
                    gp[o]  = bfhi(accl[rb][reg]);
                    h_r[o] = accr[rb][reg] + bj;
                }
            }
        }
    }
}

// ============ fused: phase-2 ELL build (blocks 0..NBUK, NO sentinel init) || gemmLR0 ==
#define MGB 1024
__global__ void __launch_bounds__(256) k_mid(const unsigned int* __restrict__ bucket,
                                             const int* __restrict__ cursor,
                                             int* __restrict__ cnt,
                                             int* __restrict__ ell,
                                             float* __restrict__ h_r,
                                             __hip_bfloat16* __restrict__ g,
                                             const float* __restrict__ Wl,
                                             const float* __restrict__ bl,
                                             const float* __restrict__ Wr) {
    __shared__ unsigned short sS[2 * 4096];
    __shared__ int lc[256];
    if (blockIdx.x < NBUK) {
        lc[threadIdx.x] = 0;
        int b = blockIdx.x;
        __syncthreads();
        int m = min(cursor[b], BCAP);
        const unsigned int* bp = bucket + (size_t)b * BCAP;
        for (int i = threadIdx.x; i < m; i += 256) {
            unsigned v = bp[i];
            int dlo = (int)(v & 255u);
            int s   = (int)(v >> 8);
            int p   = atomicAdd(&lc[dlo], 1);
            if (p < MAXD)
                ell[(((size_t)b << 8) + dlo) * MAXD + p] = s;
        }
        __syncthreads();
        int n = (b << 8) + (int)threadIdx.x;
        if (n < NN) cnt[n] = lc[threadIdx.x];
    } else {
        gemmLR_mfma(sS, threadIdx.x, MGB, blockIdx.x - NBUK, h_r, g, Wl, bl, Wr);
    }
}

#define ACCU(U) { \
    a0 += __uint_as_float((U).x << 16); a1 += __uint_as_float((U).x & 0xffff0000u); \
    a2 += __uint_as_float((U).y << 16); a3 += __uint_as_float((U).y & 0xffff0000u); \
    a4 += __uint_as_float((U).z << 16); a5 += __uint_as_float((U).z & 0xffff0000u); \
    a6 += __uint_as_float((U).w << 16); a7 += __uint_as_float((U).w & 0xffff0000u); }

// ============ FUSED gather(l) + gemmLR(l+1): one 64-node tile per block-iteration ====
#define FB 1568
__global__ void __launch_bounds__(512) k_gg(const uint4* __restrict__ gin,
                                            float* __restrict__ rA,
                                            unsigned short* __restrict__ gout,
                                            const int* __restrict__ cnt,
                                            const int* __restrict__ ell,
                                            const float* __restrict__ Wl,
                                            const float* __restrict__ bl,
                                            const float* __restrict__ Wr) {
    __shared__ unsigned short sS[2 * 4096];
    unsigned short* sP0 = sS;
    unsigned short* sP1 = sS + 4096;
    int tid = (int)threadIdx.x;
    int lane = tid & 63;
    int w    = tid >> 6;                 // 8 waves
    int cb   = w & 3;
    int rbh  = w >> 2;
    bf16x8 BLh[2], BLl[2], BRh[2], BRl[2];
    for (int i = tid; i < 4096; i += 512) {
        int k = i >> 6, c = i & 63;
        int slot = ((k >> 5) << 2) | (c >> 4);
        int ln   = (((k >> 3) & 3) << 4) | (c & 15);
        int ba   = swz((((((slot << 6) | ln) << 3) | (k & 7)) << 1));
        float wv_ = Wl[i];
        unsigned short hh = bfhi(wv_);
        *(unsigned short*)((char*)sP0 + ba) = hh;
        *(unsigned short*)((char*)sP1 + ba) = bfhi(wv_ - bf2f(hh));
    }
    __syncthreads();
#pragma unroll
    for (int ks = 0; ks < 2; ++ks) {
        int bb = swz(((((ks << 2) | cb) << 6) | lane) << 4);
        BLh[ks] = ldfrag((const char*)sP0 + bb);
        BLl[ks] = ldfrag((const char*)sP1 + bb);
    }
    __syncthreads();
    for (int i = tid; i < 4096; i += 512) {
        int k = i >> 6, c = i & 63;
        int slot = ((k >> 5) << 2) | (c >> 4);
        int ln   = (((k >> 3) & 3) << 4) | (c & 15);
        int ba   = swz((((((slot << 6) | ln) << 3) | (k & 7)) << 1));
        float wv_ = Wr[i];
        unsigned short hh = bfhi(wv_);
        *(unsigned short*)((char*)sP0 + ba) = hh;
        *(unsigned short*)((char*)sP1 + ba) = bfhi(wv_ - bf2f(hh));
    }
    __syncthreads();
#pragma unroll
    for (int ks = 0; ks < 2; ++ks) {
        int bb = swz(((((ks << 2) | cb) << 6) | lane) << 4);
        BRh[ks] = ldfrag((const char*)sP0 + bb);
        BRl[ks] = ldfrag((const char*)sP1 + bb);
    }
    int col = (cb << 4) | (lane & 15);
    float bj = bl[col];
    int r0  = (lane >> 4) << 2;
    int o   = lane >> 3;
    int c8  = lane & 7;
    for (int t = blockIdx.x; t < NTILE; t += FB) {
        int n0t = t << 6;
        int myn = n0t + (w << 3) + o;
        int d = (myn < NN) ? cnt[myn] : 0;
        int dc = min(d, MAXD);
        int dm = max(dc, __shfl_xor(dc, 8));
        dm     = max(dm, __shfl_xor(dm, 16));
        dm     = max(dm, __shfl_xor(dm, 32));
        int iters = (dm + 7) & ~7;
        const int* er = ell + ((size_t)min(myn, NN - 1) << 6) + (c8 << 3);
        int4 l0 = *(const int4*)er;
        int4 l1 = *(const int4*)(er + 4);
        float a0=0.f,a1=0.f,a2=0.f,a3=0.f,a4=0.f,a5=0.f,a6=0.f,a7=0.f;
        for (int j0 = 0; j0 < iters; j0 += 8) {
            int sl = (o << 3) | (j0 >> 3);
            int i0 = __shfl(l0.x, sl);
            int i1 = __shfl(l0.y, sl);
            int i2 = __shfl(l0.z, sl);
            int i3 = __shfl(l0.w, sl);
            int i4 = __shfl(l1.x, sl);
            int i5 = __shfl(l1.y, sl);
            int i6 = __shfl(l1.z, sl);
            int i7 = __shfl(l1.w, sl);
            i0 = (j0 + 0 < d) ? i0 : NN;
            i1 = (j0 + 1 < d) ? i1 : NN;
            i2 = (j0 + 2 < d) ? i2 : NN;
            i3 = (j0 + 3 < d) ? i3 : NN;
            i4 = (j0 + 4 < d) ? i4 : NN;
            i5 = (j0 + 5 < d) ? i5 : NN;
            i6 = (j0 + 6 < d) ? i6 : NN;
            i7 = (j0 + 7 < d) ? i7 : NN;
            uint4 u0 = gin[(size_t)i0 * 8 + c8];
            uint4 u1 = gin[(size_t)i1 * 8 + c8];
            uint4 u2 = gin[(size_t)i2 * 8 + c8];
            uint4 u3 = gin[(size_t)i3 * 8 + c8];
            uint4 u4 = gin[(size_t)i4 * 8 + c8];
            uint4 u5 = gin[(size_t)i5 * 8 + c8];
            uint4 u6 = gin[(size_t)i6 * 8 + c8];
            uint4 u7 = gin[(size_t)i7 * 8 + c8];
            ACCU(u0); ACCU(u1); ACCU(u2); ACCU(u3);
            ACCU(u4); ACCU(u5); ACCU(u6); ACCU(u7);
        }
        float4 rv0 = make_float4(0.f,0.f,0.f,0.f), rv1 = rv0;
        if (myn < NN) {
            float inv = 1.0f / fmaxf((float)d, 1.0f);
            const float4* rp = (const float4*)(rA + ((size_t)myn << 6) + (c8 << 3));
            rv0 = rp[0]; rv1 = rp[1];
            rv0.x = fmaxf(fmaf(a0, inv, rv0.x), 0.0f);
            rv0.y = fmaxf(fmaf(a1, inv, rv0.y), 0.0f);
            rv0.z = fmaxf(fmaf(a2, inv, rv0.z), 0.0f);
            rv0.w = fmaxf(fmaf(a3, inv, rv0.w), 0.0f);
            rv1.x = fmaxf(fmaf(a4, inv, rv1.x), 0.0f);
            rv1.y = fmaxf(fmaf(a5, inv, rv1.y), 0.0f);
            rv1.z = fmaxf(fmaf(a6, inv, rv1.z), 0.0f);
            rv1.w = fmaxf(fmaf(a7, inv, rv1.w), 0.0f);
        }
        __syncthreads();
        {
            int rr = (w << 3) + o;
#pragma unroll
            for (int half = 0; half < 2; ++half) {
                float4 v = half ? rv1 : rv0;
                int k0 = (c8 << 3) + (half << 2);
                int slot = ((k0 >> 5) << 2) | (rr >> 4);
                int ln   = (((k0 >> 3) & 3) << 4) | (rr & 15);
                int ba   = swz((((((slot << 6) | ln) << 3) | (k0 & 7)) << 1));
                unsigned short h0 = bfhi(v.x), h1 = bfhi(v.y),
                               h2 = bfhi(v.z), h3 = bfhi(v.w);
                *(ushort4*)((char*)sP0 + ba) = make_ushort4(h0, h1, h2, h3);
                *(ushort4*)((char*)sP1 + ba) = make_ushort4(
                    bfhi(v.x - bf2f(h0)), bfhi(v.y - bf2f(h1)),
                    bfhi(v.z - bf2f(h2)), bfhi(v.w - bf2f(h3)));
            }
        }
        __syncthreads();
        f32x4 accl[2] = {{0.f,0.f,0.f,0.f},{0.f,0.f,0.f,0.f}};
        f32x4 accr[2] = {{0.f,0.f,0.f,0.f},{0.f,0.f,0.f,0.f}};
#pragma unroll
        for (int ks = 0; ks < 2; ++ks) {
#pragma unroll
            for (int rl = 0; rl < 2; ++rl) {
                int rb = (rbh << 1) | rl;
                int ab = swz(((((ks << 2) | rb) << 6) | lane) << 4);
                bf16x8 ah = ldfrag((const char*)sP0 + ab);
                bf16x8 al = ldfrag((const char*)sP1 + ab);
                accl[rl] = __builtin_amdgcn_mfma_f32_16x16x32_bf16(ah, BLh[ks], accl[rl], 0, 0, 0);
                accl[rl] = __builtin_amdgcn_mfma_f32_16x16x32_bf16(ah, BLl[ks], accl[rl], 0, 0, 0);
                accl[rl] = __builtin_amdgcn_mfma_f32_16x16x32_bf16(al, BLh[ks], accl[rl], 0, 0, 0);
                accr[rl] = __builtin_amdgcn_mfma_f32_16x16x32_bf16(ah, BRh[ks], accr[rl], 0, 0, 0);
                accr[rl] = __builtin_amdgcn_mfma_f32_16x16x32_bf16(ah, BRl[ks], accr[rl], 0, 0, 0);
                accr[rl] = __builtin_amdgcn_mfma_f32_16x16x32_bf16(al, BRh[ks], accr[rl], 0, 0, 0);
            }
        }
#pragma unroll
        for (int rl = 0; rl < 2; ++rl) {
            int rb = (rbh << 1) | rl;
#pragma unroll
            for (int reg = 0; reg < 4; ++reg) {
                int row = (rb << 4) + r0 + reg;
                int n = n0t + row;
                if (n < NN) {
                    size_t off = ((size_t)n << 6) + col;
                    gout[off] = bfhi(accl[rl][reg]);
                    rA[off]   = accr[rl][reg] + bj;
                }
            }
        }
    }
}

// ============ FUSED final gather (layer 2) + global mean pool accumulate ============
// h3 never touches HBM: gather -> relu rows in regs -> wave-level batch reduction
// (fast path: all 8 nodes same graph, ~96% given 195 nodes/graph) -> pool atomics.
__global__ void __launch_bounds__(256) k_gpool(const uint4* __restrict__ g4,
                                               const float* __restrict__ rA,
                                               const int* __restrict__ cnt,
                                               const int* __restrict__ ell,
                                               const int* __restrict__ batch,
                                               float* __restrict__ pool,
                                               float* __restrict__ cntg) {
    int lane = threadIdx.x & 63;
    int o    = lane >> 3;
    int c8   = lane & 7;
    int wv = __builtin_amdgcn_readfirstlane((int)((blockIdx.x * 256 + threadIdx.x) >> 6));
    int nw = (gridDim.x * 256) >> 6;
    for (int p = wv; p < NN / 8; p += nw) {
        int myn = 8 * p + o;
        int d   = cnt[myn];
        int dc  = min(d, MAXD);
        int dm  = max(dc, __shfl_xor(dc, 8));
        dm      = max(dm, __shfl_xor(dm, 16));
        dm      = max(dm, __shfl_xor(dm, 32));
        int iters = (dm + 7) & ~7;
        const int* er = ell + ((size_t)myn << 6) + (c8 << 3);
        int4 l0 = *(const int4*)er;
        int4 l1 = *(const int4*)(er + 4);
        float a0=0.f,a1=0.f,a2=0.f,a3=0.f,a4=0.f,a5=0.f,a6=0.f,a7=0.f;
        for (int j0 = 0; j0 < iters; j0 += 8) {
            int sl = (o << 3) | (j0 >> 3);
            int i0 = __shfl(l0.x, sl);
            int i1 = __shfl(l0.y, sl);
            int i2 = __shfl(l0.z, sl);
            int i3 = __shfl(l0.w, sl);
            int i4 = __shfl(l1.x, sl);
            int i5 = __shfl(l1.y, sl);
            int i6 = __shfl(l1.z, sl);
            int i7 = __shfl(l1.w, sl);
            i0 = (j0 + 0 < d) ? i0 : NN;
            i1 = (j0 + 1 < d) ? i1 : NN;
            i2 = (j0 + 2 < d) ? i2 : NN;
            i3 = (j0 + 3 < d) ? i3 : NN;
            i4 = (j0 + 4 < d) ? i4 : NN;
            i5 = (j0 + 5 < d) ? i5 : NN;
            i6 = (j0 + 6 < d) ? i6 : NN;
            i7 = (j0 + 7 < d) ? i7 : NN;
            uint4 u0 = g4[(size_t)i0 * 8 + c8];
            uint4 u1 = g4[(size_t)i1 * 8 + c8];
            uint4 u2 = g4[(size_t)i2 * 8 + c8];
            uint4 u3 = g4[(size_t)i3 * 8 + c8];
            uint4 u4 = g4[(size_t)i4 * 8 + c8];
            uint4 u5 = g4[(size_t)i5 * 8 + c8];
            uint4 u6 = g4[(size_t)i6 * 8 + c8];
            uint4 u7 = g4[(size_t)i7 * 8 + c8];
            ACCU(u0); ACCU(u1); ACCU(u2); ACCU(u3);
            ACCU(u4); ACCU(u5); ACCU(u6); ACCU(u7);
        }
        float inv = 1.0f / fmaxf((float)d, 1.0f);
        const float4* rp = (const float4*)(rA + ((size_t)myn << 6) + (c8 << 3));
        float4 rv0 = rp[0], rv1 = rp[1];
        float v0 = fmaxf(fmaf(a0, inv, rv0.x), 0.0f);
        float v1 = fmaxf(fmaf(a1, inv, rv0.y), 0.0f);
        float v2 = fmaxf(fmaf(a2, inv, rv0.z), 0.0f);
        float v3 = fmaxf(fmaf(a3, inv, rv0.w), 0.0f);
        float v4 = fmaxf(fmaf(a4, inv, rv1.x), 0.0f);
        float v5 = fmaxf(fmaf(a5, inv, rv1.y), 0.0f);
        float v6 = fmaxf(fmaf(a6, inv, rv1.z), 0.0f);
        float v7 = fmaxf(fmaf(a7, inv, rv1.w), 0.0f);
        int b  = batch[myn];
        int b0 = __shfl(b, c8);            // o=0's batch id (wave-uniform per c8 group)
        if (__all(b == b0)) {
            // tree-sum over the 8 nodes (lanes differing in bits 3..5)
#pragma unroll
            for (int m = 8; m <= 32; m <<= 1) {
                v0 += __shfl_xor(v0, m); v1 += __shfl_xor(v1, m);
                v2 += __shfl_xor(v2, m); v3 += __shfl_xor(v3, m);
                v4 += __shfl_xor(v4, m); v5 += __shfl_xor(v5, m);
                v6 += __shfl_xor(v6, m); v7 += __shfl_xor(v7, m);
            }
            if (o == 0) {
                float* pb = pool + ((size_t)b0 << 6) + (c8 << 3);
                atomicAdd(pb + 0, v0); atomicAdd(pb + 1, v1);
                atomicAdd(pb + 2, v2); atomicAdd(pb + 3, v3);
                atomicAdd(pb + 4, v4); atomicAdd(pb + 5, v5);
                atomicAdd(pb + 6, v6); atomicAdd(pb + 7, v7);
                if (c8 == 0) atomicAdd(&cntg[b0], 8.0f);
            }
        } else {
            float* pb = pool + ((size_t)b << 6) + (c8 << 3);
            atomicAdd(pb + 0, v0); atomicAdd(pb + 1, v1);
            atomicAdd(pb + 2, v2); atomicAdd(pb + 3, v3);
            atomicAdd(pb + 4, v4); atomicAdd(pb + 5, v5);
            atomicAdd(pb + 6, v6); atomicAdd(pb + 7, v7);
            if (c8 == 0) atomicAdd(&cntg[b], 1.0f);
        }
    }
}

// ============ output GEMM ============
__global__ void __launch_bounds__(256) k_out(const float* __restrict__ pool,
                                             const float* __restrict__ cntg,
                                             const float* __restrict__ W1,
                                             const float* __restrict__ b1,
                                             float* __restrict__ out) {
    __shared__ float sW[64 * 64];
    for (int i = threadIdx.x; i < 64 * 64; i += 256) sW[i] = W1[i];
    __syncthreads();
    int lane = threadIdx.x & 63;
    int wid  = (blockIdx.x * 256 + threadIdx.x) >> 6;
    int nw   = (gridDim.x * 256) >> 6;
    for (int gidx = wid; gidx < NG; gidx += nw) {
        float ic = 1.0f / fmaxf(cntg[gidx], 1.0f);
        float acc = 0.0f;
#pragma unroll
        for (int k = 0; k < 64; ++k)
            acc = fmaf(pool[(size_t)gidx * 64 + k], sW[k * 64 + lane], acc);
        out[(size_t)gidx * 64 + lane] = fmaf(acc, ic, b1[lane]);
    }
}

extern "C" void kernel_launch(void* const* d_in, const int* in_sizes, int n_in,
                              void* d_out, int out_size, void* d_ws, size_t ws_size,
                              hipStream_t stream) {
    const float* x     = (const float*)d_in[0];
    const int*   ei    = (const int*)d_in[1];   // [2,E]
    const int*   batch = (const int*)d_in[3];
    const float* W0    = (const float*)d_in[4];
    const float* b0    = (const float*)d_in[5];
    const float* Wl    = (const float*)d_in[6];
    const float* bl    = (const float*)d_in[7];
    const float* Wr    = (const float*)d_in[8];
    const float* W1    = (const float*)d_in[9];
    const float* b1    = (const float*)d_in[10];
    float* out = (float*)d_out;

    char* ws = (char*)d_ws;
    size_t off = 0;
    auto alloc = [&](size_t bytes) -> void* {
        void* p = ws + off;
        off += (bytes + 255) & ~(size_t)255;
        return p;
    };
    float*          A  = (float*)alloc((size_t)NN * 64 * 4);              // h / r (in-place)
    unsigned short* G0 = (unsigned short*)alloc((size_t)NN * 128);        // g ping
    size_t z1start = off;
    (void)alloc(256);                                                     // G0 zero row (row NN)
    unsigned short* G1 = (unsigned short*)alloc((size_t)NN * 128);        // g pong
    size_t z2start = off;
    (void)alloc(256);                                                     // G1 zero row (row NN)
    int*   cursor = (int*)alloc((size_t)NBUK * 4);
    float* pool   = (float*)alloc((size_t)NG * 64 * 4);
    float* cntg   = (float*)alloc((size_t)NG * 4);
    size_t z2len = off - z2start;
    int*          ell    = (int*)alloc((size_t)NN * MAXD * 4);            // ELL (tails garbage, masked)
    unsigned int* bucket = (unsigned int*)alloc((size_t)NBUK * BCAP * 4);
    int*          cnt    = (int*)alloc((size_t)NN * 4);                   // fully written by k_mid

    const int* src = ei;
    const int* dst = ei + NE;

    hipMemsetAsync(ws + z1start, 0, 256, stream);          // G0 zero row
    hipMemsetAsync(ws + z2start, 0, z2len, stream);        // G1 zero row + cursor + pool + cntg

    // phase-1 binning || input projection (MFMA)
    k_front<<<NBUK + GB, 512, 0, stream>>>(src, dst, cursor, bucket, x, W0, b0, A);
    // phase-2 ELL build (no sentinel init) || gemmLR layer 0 -> G0, r0
    k_mid<<<NBUK + MGB, 256, 0, stream>>>(bucket, cursor, cnt, ell, A,
                                          (__hip_bfloat16*)G0, Wl, bl, Wr);
    // fused gather0 + gemmLR1: G0 -> G1
    k_gg<<<FB, 512, 0, stream>>>((const uint4*)G0, A, G1, cnt, ell,
                                 Wl + (size_t)1 * 64 * 64, bl + 64, Wr + (size_t)1 * 64 * 64);
    // fused gather1 + gemmLR2: G1 -> G0
    k_gg<<<FB, 512, 0, stream>>>((const uint4*)G1, A, G0, cnt, ell,
                                 Wl + (size_t)2 * 64 * 64, bl + 128, Wr + (size_t)2 * 64 * 64);
    // fused final gather (layer 2) + mean-pool accumulate
    k_gpool<<<3125, 256, 0, stream>>>((const uint4*)G0, A, cnt, ell, batch, pool, cntg);

    k_out<<<128, 256, 0, stream>>>(pool, cntg, W1, b1, out);
}

// Round 9
// 387.416 us; speedup vs baseline: 1.1167x; 1.1167x over previous
//
#include <hip/hip_runtime.h>
#include <hip/hip_bf16.h>

#define NN 100000
#define NE 1600000
#define DIN 128
#define NG 512
#define MAXD 64
#define NBUK 391               // dst>>8 buckets (256 nodes each)
#define BCAP 5120              // mean 4092, +16 sigma
#define CHUNK ((NE + NBUK - 1) / NBUK)
#define NTILE ((NN + 63) >> 6)  // 64-node tiles

typedef __attribute__((ext_vector_type(8))) __bf16 bf16x8;
typedef __attribute__((ext_vector_type(4))) float f32x4;

static __device__ __forceinline__ unsigned short bfhi(float f) {
    __hip_bfloat16 h = __float2bfloat16(f);
    return *reinterpret_cast<unsigned short*>(&h);
}
static __device__ __forceinline__ float bf2f(unsigned short u) {
    unsigned v = (unsigned)u << 16;
    return __uint_as_float(v);
}
static __device__ __forceinline__ bf16x8 ldfrag(const void* p) {
    bf16x8 r;
    __builtin_memcpy(&r, p, 16);
    return r;
}
// LDS frag-bank swizzle: XOR bits>=4 only (8B writes / 16B reads stay aligned).
static __device__ __forceinline__ int swz(int a) {
    return a ^ (((a >> 8) & 3) << 5) ^ (((a >> 12) & 3) << 4);
}

// Fragment addressing (mfma_f32_16x16x32_bf16):
//  A: lane l holds A[R0 + (l&15)][32*ks + 8*(l>>4) + j], j=0..7
//  B: lane l holds B[32*ks + 8*(l>>4) + j][C0 + (l&15)]
//  C/D: col = C0 + (lane&15), row = R0 + (lane>>4)*4 + reg   [verified layout]
// LDS frag order: byte = swz( (((slot*64 + lane)*8 + j) * 2) ), slot = ks*4 + rb/cb.
// GRID SIZING [round-8 lesson]: per-block W-prepack is the dominant fixed cost;
// blocks must process >=3 tiles each (FB=512, MGB=512). Larger grids regress.

// ============ fused: phase-1 binning (blocks 0..NBUK) || input GEMM (rest) ============
#define GB 256
__global__ void __launch_bounds__(512) k_front(const int* __restrict__ src,
                                               const int* __restrict__ dst,
                                               int* __restrict__ cursor,
                                               unsigned int* __restrict__ bucket,
                                               const float* __restrict__ x,
                                               const float* __restrict__ W0,
                                               const float* __restrict__ b0,
                                               float* __restrict__ h) {
    __shared__ unsigned short sS[2 * 8192];   // 2 planes x 16 KB (W0 prepack, then x tiles)
    __shared__ int lcnt[NBUK];
    __shared__ int lbase[NBUK];
    if (blockIdx.x < NBUK) {
        for (int i = threadIdx.x; i < NBUK; i += 512) lcnt[i] = 0;
        __syncthreads();
        int e0 = blockIdx.x * CHUNK;
        int e1 = min(e0 + CHUNK, NE);
        for (int e = e0 + (int)threadIdx.x; e < e1; e += 512)
            atomicAdd(&lcnt[dst[e] >> 8], 1);
        __syncthreads();
        for (int i = threadIdx.x; i < NBUK; i += 512) {
            int c = lcnt[i];
            lbase[i] = c ? atomicAdd(&cursor[i], c) : 0;
            lcnt[i] = 0;
        }
        __syncthreads();
        for (int e = e0 + (int)threadIdx.x; e < e1; e += 512) {
            int d = dst[e];
            int s = src[e];
            int bk = d >> 8;
            int pos = lbase[bk] + atomicAdd(&lcnt[bk], 1);
            if (pos < BCAP)
                bucket[(size_t)bk * BCAP + pos] = ((unsigned)s << 8) | (unsigned)(d & 255);
        }
    } else {
        // ---- input GEMM via MFMA bf16x3: h = relu(x @ W0 + b0) ----
        unsigned short* sP0 = sS;
        unsigned short* sP1 = sS + 8192;
        for (int i = threadIdx.x; i < 8192; i += 512) {
            int k = i >> 6, c = i & 63;
            int slot = ((k >> 5) << 2) | (c >> 4);
            int ln   = (((k >> 3) & 3) << 4) | (c & 15);
            int ba   = swz((((((slot << 6) | ln) << 3) | (k & 7)) << 1));
            float w0 = W0[i];
            unsigned short hh = bfhi(w0);
            *(unsigned short*)((char*)sP0 + ba) = hh;
            *(unsigned short*)((char*)sP1 + ba) = bfhi(w0 - bf2f(hh));
        }
        __syncthreads();
        int lane = threadIdx.x & 63;
        int wv   = threadIdx.x >> 6;
        int cb   = wv & 3;
        int rbh  = wv >> 2;
        int col  = (cb << 4) | (lane & 15);
        float bj = b0[col];
        int r0   = (lane >> 4) << 2;
        bf16x8 Bh[4], Bl[4];
#pragma unroll
        for (int ks = 0; ks < 4; ++ks) {
            int bb = swz(((((ks << 2) | cb) << 6) | lane) << 4);
            Bh[ks] = ldfrag((const char*)sP0 + bb);
            Bl[ks] = ldfrag((const char*)sP1 + bb);
        }
        for (int t = blockIdx.x - NBUK; t < NTILE; t += GB) {
            int n0 = t << 6;
            __syncthreads();
#pragma unroll
            for (int i = 0; i < 4; ++i) {
                int tau = (int)threadIdx.x + (i << 9);
                int r = tau >> 5, kq = tau & 31;
                int n = n0 + r;
                float4 v = make_float4(0.f, 0.f, 0.f, 0.f);
                if (n < NN) v = *(const float4*)(x + ((size_t)n << 7) + (kq << 2));
                int k0   = kq << 2;
                int slot = ((k0 >> 5) << 2) | (r >> 4);
                int ln   = (((k0 >> 3) & 3) << 4) | (r & 15);
                int ba   = swz((((((slot << 6) | ln) << 3) | (k0 & 7)) << 1));
                unsigned short h0 = bfhi(v.x), h1 = bfhi(v.y),
                               h2 = bfhi(v.z), h3 = bfhi(v.w);
                *(ushort4*)((char*)sP0 + ba) = make_ushort4(h0, h1, h2, h3);
                *(ushort4*)((char*)sP1 + ba) = make_ushort4(
                    bfhi(v.x - bf2f(h0)), bfhi(v.y - bf2f(h1)),
                    bfhi(v.z - bf2f(h2)), bfhi(v.w - bf2f(h3)));
            }
            __syncthreads();
            f32x4 acc[2] = {{0.f,0.f,0.f,0.f},{0.f,0.f,0.f,0.f}};
#pragma unroll
            for (int ks = 0; ks < 4; ++ks) {
#pragma unroll
                for (int rl = 0; rl < 2; ++rl) {
                    int rb = (rbh << 1) | rl;
                    int ab = swz(((((ks << 2) | rb) << 6) | lane) << 4);
                    bf16x8 ah = ldfrag((const char*)sP0 + ab);
                    bf16x8 al = ldfrag((const char*)sP1 + ab);
                    acc[rl] = __builtin_amdgcn_mfma_f32_16x16x32_bf16(ah, Bh[ks], acc[rl], 0, 0, 0);
                    acc[rl] = __builtin_amdgcn_mfma_f32_16x16x32_bf16(ah, Bl[ks], acc[rl], 0, 0, 0);
                    acc[rl] = __builtin_amdgcn_mfma_f32_16x16x32_bf16(al, Bh[ks], acc[rl], 0, 0, 0);
                }
            }
#pragma unroll
            for (int rl = 0; rl < 2; ++rl) {
                int rb = (rbh << 1) | rl;
#pragma unroll
                for (int reg = 0; reg < 4; ++reg) {
                    int row = (rb << 4) + r0 + reg;
                    int n = n0 + row;
                    if (n < NN)
                        h[((size_t)n << 6) + col] = fmaxf(acc[rl][reg] + bj, 0.f);
                }
            }
        }
    }
}

// ---- gemmLR via MFMA bf16x3 (4-wave body, used by k_mid layer 0) ----
__device__ __forceinline__ void gemmLR_mfma(unsigned short* sS,
                                            int tid, int nblk, int bidx,
                                            float* __restrict__ h_r,
                                            __hip_bfloat16* __restrict__ g,
                                            const float* __restrict__ Wl,
                                            const float* __restrict__ bl,
                                            const float* __restrict__ Wr) {
    unsigned short* sP0 = sS;
    unsigned short* sP1 = sS + 4096;
    int lane = tid & 63;
    int cb   = tid >> 6;
    bf16x8 BLh[2], BLl[2], BRh[2], BRl[2];
    for (int i = tid; i < 4096; i += 256) {
        int k = i >> 6, c = i & 63;
        int slot = ((k >> 5) << 2) | (c >> 4);
        int ln   = (((k >> 3) & 3) << 4) | (c & 15);
        int ba   = swz((((((slot << 6) | ln) << 3) | (k & 7)) << 1));
        float w = Wl[i];
        unsigned short hh = bfhi(w);
        *(unsigned short*)((char*)sP0 + ba) = hh;
        *(unsigned short*)((char*)sP1 + ba) = bfhi(w - bf2f(hh));
    }
    __syncthreads();
#pragma unroll
    for (int ks = 0; ks < 2; ++ks) {
        int bb = swz(((((ks << 2) | cb) << 6) | lane) << 4);
        BLh[ks] = ldfrag((const char*)sP0 + bb);
        BLl[ks] = ldfrag((const char*)sP1 + bb);
    }
    __syncthreads();
    for (int i = tid; i < 4096; i += 256) {
        int k = i >> 6, c = i & 63;
        int slot = ((k >> 5) << 2) | (c >> 4);
        int ln   = (((k >> 3) & 3) << 4) | (c & 15);
        int ba   = swz((((((slot << 6) | ln) << 3) | (k & 7)) << 1));
        float w = Wr[i];
        unsigned short hh = bfhi(w);
        *(unsigned short*)((char*)sP0 + ba) = hh;
        *(unsigned short*)((char*)sP1 + ba) = bfhi(w - bf2f(hh));
    }
    __syncthreads();
#pragma unroll
    for (int ks = 0; ks < 2; ++ks) {
        int bb = swz(((((ks << 2) | cb) << 6) | lane) << 4);
        BRh[ks] = ldfrag((const char*)sP0 + bb);
        BRl[ks] = ldfrag((const char*)sP1 + bb);
    }
    int col = (cb << 4) | (lane & 15);
    float bj = bl[col];
    int r0  = (lane >> 4) << 2;
    unsigned short* gp = (unsigned short*)g;
    for (int t = bidx; t < NTILE; t += nblk) {
        int n0 = t << 6;
        __syncthreads();
#pragma unroll
        for (int i = 0; i < 4; ++i) {
            int tau = tid + (i << 8);
            int r = tau >> 4, kq = tau & 15;
            int n = n0 + r;
            float4 v = make_float4(0.f, 0.f, 0.f, 0.f);
            if (n < NN) v = *(const float4*)(h_r + ((size_t)n << 6) + (kq << 2));
            int k0   = kq << 2;
            int slot = ((k0 >> 5) << 2) | (r >> 4);
            int ln   = (((k0 >> 3) & 3) << 4) | (r & 15);
            int ba   = swz((((((slot << 6) | ln) << 3) | (k0 & 7)) << 1));
            unsigned short h0 = bfhi(v.x), h1 = bfhi(v.y),
                           h2 = bfhi(v.z), h3 = bfhi(v.w);
            *(ushort4*)((char*)sP0 + ba) = make_ushort4(h0, h1, h2, h3);
            *(ushort4*)((char*)sP1 + ba) = make_ushort4(
                bfhi(v.x - bf2f(h0)), bfhi(v.y - bf2f(h1)),
                bfhi(v.z - bf2f(h2)), bfhi(v.w - bf2f(h3)));
        }
        __syncthreads();
        f32x4 accl[4] = {{0.f,0.f,0.f,0.f},{0.f,0.f,0.f,0.f},
                         {0.f,0.f,0.f,0.f},{0.f,0.f,0.f,0.f}};
        f32x4 accr[4] = {{0.f,0.f,0.f,0.f},{0.f,0.f,0.f,0.f},
                         {0.f,0.f,0.f,0.f},{0.f,0.f,0.f,0.f}};
#pragma unroll
        for (int ks = 0; ks < 2; ++ks) {
#pragma unroll
            for (int rb = 0; rb < 4; ++rb) {
                int ab = swz(((((ks << 2) | rb) << 6) | lane) << 4);
                bf16x8 ah = ldfrag((const char*)sP0 + ab);
                bf16x8 al = ldfrag((const char*)sP1 + ab);
                accl[rb] = __builtin_amdgcn_mfma_f32_16x16x32_bf16(ah, BLh[ks], accl[rb], 0, 0, 0);
                accl[rb] = __builtin_amdgcn_mfma_f32_16x16x32_bf16(ah, BLl[ks], accl[rb], 0, 0, 0);
                accl[rb] = __builtin_amdgcn_mfma_f32_16x16x32_bf16(al, BLh[ks], accl[rb], 0, 0, 0);
                accr[rb] = __builtin_amdgcn_mfma_f32_16x16x32_bf16(ah, BRh[ks], accr[rb], 0, 0, 0);
                accr[rb] = __builtin_amdgcn_mfma_f32_16x16x32_bf16(ah, BRl[ks], accr[rb], 0, 0, 0);
                accr[rb] = __builtin_amdgcn_mfma_f32_16x16x32_bf16(al, BRh[ks], accr[rb], 0, 0, 0);
            }
        }
#pragma unroll
        for (int rb = 0; rb < 4; ++rb) {
#pragma unroll
            for (int reg = 0; reg < 4; ++reg) {
                int row = (rb << 4) + r0 + reg;
                int n = n0 + row;
                if (n < NN) {
                    size_t o = ((size_t)n << 6) + col;
                    gp[o]  = bfhi(accl[rb][reg]);
                    h_r[o] = accr[rb][reg] + bj;
                }
            }
        }
    }
}

// ============ fused: phase-2 ELL build (blocks 0..NBUK, NO sentinel init) || gemmLR0 ==
#define MGB 512
__global__ void __launch_bounds__(256) k_mid(const unsigned int* __restrict__ bucket,
                                             const int* __restrict__ cursor,
                                             int* __restrict__ cnt,
                                             int* __restrict__ ell,
                                             float* __restrict__ h_r,
                                             __hip_bfloat16* __restrict__ g,
                                             const float* __restrict__ Wl,
                                             const float* __restrict__ bl,
                                             const float* __restrict__ Wr) {
    __shared__ unsigned short sS[2 * 4096];
    __shared__ int lc[256];
    if (blockIdx.x < NBUK) {
        lc[threadIdx.x] = 0;
        int b = blockIdx.x;
        __syncthreads();
        int m = min(cursor[b], BCAP);
        const unsigned int* bp = bucket + (size_t)b * BCAP;
        for (int i = threadIdx.x; i < m; i += 256) {
            unsigned v = bp[i];
            int dlo = (int)(v & 255u);
            int s   = (int)(v >> 8);
            int p   = atomicAdd(&lc[dlo], 1);
            if (p < MAXD)
                ell[(((size_t)b << 8) + dlo) * MAXD + p] = s;
        }
        __syncthreads();
        int n = (b << 8) + (int)threadIdx.x;
        if (n < NN) cnt[n] = lc[threadIdx.x];
    } else {
        gemmLR_mfma(sS, threadIdx.x, MGB, blockIdx.x - NBUK, h_r, g, Wl, bl, Wr);
    }
}

#define ACCU(U) { \
    a0 += __uint_as_float((U).x << 16); a1 += __uint_as_float((U).x & 0xffff0000u); \
    a2 += __uint_as_float((U).y << 16); a3 += __uint_as_float((U).y & 0xffff0000u); \
    a4 += __uint_as_float((U).z << 16); a5 += __uint_as_float((U).z & 0xffff0000u); \
    a6 += __uint_as_float((U).w << 16); a7 += __uint_as_float((U).w & 0xffff0000u); }

// ============ FUSED gather(l) + gemmLR(l+1): one 64-node tile per block-iteration ====
#define FB 512
__global__ void __launch_bounds__(512) k_gg(const uint4* __restrict__ gin,
                                            float* __restrict__ rA,
                                            unsigned short* __restrict__ gout,
                                            const int* __restrict__ cnt,
                                            const int* __restrict__ ell,
                                            const float* __restrict__ Wl,
                                            const float* __restrict__ bl,
                                            const float* __restrict__ Wr) {
    __shared__ unsigned short sS[2 * 4096];
    unsigned short* sP0 = sS;
    unsigned short* sP1 = sS + 4096;
    int tid = (int)threadIdx.x;
    int lane = tid & 63;
    int w    = tid >> 6;                 // 8 waves
    int cb   = w & 3;
    int rbh  = w >> 2;
    bf16x8 BLh[2], BLl[2], BRh[2], BRl[2];
    for (int i = tid; i < 4096; i += 512) {
        int k = i >> 6, c = i & 63;
        int slot = ((k >> 5) << 2) | (c >> 4);
        int ln   = (((k >> 3) & 3) << 4) | (c & 15);
        int ba   = swz((((((slot << 6) | ln) << 3) | (k & 7)) << 1));
        float wv_ = Wl[i];
        unsigned short hh = bfhi(wv_);
        *(unsigned short*)((char*)sP0 + ba) = hh;
        *(unsigned short*)((char*)sP1 + ba) = bfhi(wv_ - bf2f(hh));
    }
    __syncthreads();
#pragma unroll
    for (int ks = 0; ks < 2; ++ks) {
        int bb = swz(((((ks << 2) | cb) << 6) | lane) << 4);
        BLh[ks] = ldfrag((const char*)sP0 + bb);
        BLl[ks] = ldfrag((const char*)sP1 + bb);
    }
    __syncthreads();
    for (int i = tid; i < 4096; i += 512) {
        int k = i >> 6, c = i & 63;
        int slot = ((k >> 5) << 2) | (c >> 4);
        int ln   = (((k >> 3) & 3) << 4) | (c & 15);
        int ba   = swz((((((slot << 6) | ln) << 3) | (k & 7)) << 1));
        float wv_ = Wr[i];
        unsigned short hh = bfhi(wv_);
        *(unsigned short*)((char*)sP0 + ba) = hh;
        *(unsigned short*)((char*)sP1 + ba) = bfhi(wv_ - bf2f(hh));
    }
    __syncthreads();
#pragma unroll
    for (int ks = 0; ks < 2; ++ks) {
        int bb = swz(((((ks << 2) | cb) << 6) | lane) << 4);
        BRh[ks] = ldfrag((const char*)sP0 + bb);
        BRl[ks] = ldfrag((const char*)sP1 + bb);
    }
    int col = (cb << 4) | (lane & 15);
    float bj = bl[col];
    int r0  = (lane >> 4) << 2;
    int o   = lane >> 3;
    int c8  = lane & 7;
    for (int t = blockIdx.x; t < NTILE; t += FB) {
        int n0t = t << 6;
        int myn = n0t + (w << 3) + o;
        int d = (myn < NN) ? cnt[myn] : 0;
        int dc = min(d, MAXD);
        int dm = max(dc, __shfl_xor(dc, 8));
        dm     = max(dm, __shfl_xor(dm, 16));
        dm     = max(dm, __shfl_xor(dm, 32));
        int iters = (dm + 7) & ~7;
        const int* er = ell + ((size_t)min(myn, NN - 1) << 6) + (c8 << 3);
        int4 l0 = *(const int4*)er;
        int4 l1 = *(const int4*)(er + 4);
        float a0=0.f,a1=0.f,a2=0.f,a3=0.f,a4=0.f,a5=0.f,a6=0.f,a7=0.f;
        for (int j0 = 0; j0 < iters; j0 += 8) {
            int sl = (o << 3) | (j0 >> 3);
            int i0 = __shfl(l0.x, sl);
            int i1 = __shfl(l0.y, sl);
            int i2 = __shfl(l0.z, sl);
            int i3 = __shfl(l0.w, sl);
            int i4 = __shfl(l1.x, sl);
            int i5 = __shfl(l1.y, sl);
            int i6 = __shfl(l1.z, sl);
            int i7 = __shfl(l1.w, sl);
            i0 = (j0 + 0 < d) ? i0 : NN;
            i1 = (j0 + 1 < d) ? i1 : NN;
            i2 = (j0 + 2 < d) ? i2 : NN;
            i3 = (j0 + 3 < d) ? i3 : NN;
            i4 = (j0 + 4 < d) ? i4 : NN;
            i5 = (j0 + 5 < d) ? i5 : NN;
            i6 = (j0 + 6 < d) ? i6 : NN;
            i7 = (j0 + 7 < d) ? i7 : NN;
            uint4 u0 = gin[(size_t)i0 * 8 + c8];
            uint4 u1 = gin[(size_t)i1 * 8 + c8];
            uint4 u2 = gin[(size_t)i2 * 8 + c8];
            uint4 u3 = gin[(size_t)i3 * 8 + c8];
            uint4 u4 = gin[(size_t)i4 * 8 + c8];
            uint4 u5 = gin[(size_t)i5 * 8 + c8];
            uint4 u6 = gin[(size_t)i6 * 8 + c8];
            uint4 u7 = gin[(size_t)i7 * 8 + c8];
            ACCU(u0); ACCU(u1); ACCU(u2); ACCU(u3);
            ACCU(u4); ACCU(u5); ACCU(u6); ACCU(u7);
        }
        float4 rv0 = make_float4(0.f,0.f,0.f,0.f), rv1 = rv0;
        if (myn < NN) {
            float inv = 1.0f / fmaxf((float)d, 1.0f);
            const float4* rp = (const float4*)(rA + ((size_t)myn << 6) + (c8 << 3));
            rv0 = rp[0]; rv1 = rp[1];
            rv0.x = fmaxf(fmaf(a0, inv, rv0.x), 0.0f);
            rv0.y = fmaxf(fmaf(a1, inv, rv0.y), 0.0f);
            rv0.z = fmaxf(fmaf(a2, inv, rv0.z), 0.0f);
            rv0.w = fmaxf(fmaf(a3, inv, rv0.w), 0.0f);
            rv1.x = fmaxf(fmaf(a4, inv, rv1.x), 0.0f);
            rv1.y = fmaxf(fmaf(a5, inv, rv1.y), 0.0f);
            rv1.z = fmaxf(fmaf(a6, inv, rv1.z), 0.0f);
            rv1.w = fmaxf(fmaf(a7, inv, rv1.w), 0.0f);
        }
        __syncthreads();
        {
            int rr = (w << 3) + o;
#pragma unroll
            for (int half = 0; half < 2; ++half) {
                float4 v = half ? rv1 : rv0;
                int k0 = (c8 << 3) + (half << 2);
                int slot = ((k0 >> 5) << 2) | (rr >> 4);
                int ln   = (((k0 >> 3) & 3) << 4) | (rr & 15);
                int ba   = swz((((((slot << 6) | ln) << 3) | (k0 & 7)) << 1));
                unsigned short h0 = bfhi(v.x), h1 = bfhi(v.y),
                               h2 = bfhi(v.z), h3 = bfhi(v.w);
                *(ushort4*)((char*)sP0 + ba) = make_ushort4(h0, h1, h2, h3);
                *(ushort4*)((char*)sP1 + ba) = make_ushort4(
                    bfhi(v.x - bf2f(h0)), bfhi(v.y - bf2f(h1)),
                    bfhi(v.z - bf2f(h2)), bfhi(v.w - bf2f(h3)));
            }
        }
        __syncthreads();
        f32x4 accl[2] = {{0.f,0.f,0.f,0.f},{0.f,0.f,0.f,0.f}};
        f32x4 accr[2] = {{0.f,0.f,0.f,0.f},{0.f,0.f,0.f,0.f}};
#pragma unroll
        for (int ks = 0; ks < 2; ++ks) {
#pragma unroll
            for (int rl = 0; rl < 2; ++rl) {
                int rb = (rbh << 1) | rl;
                int ab = swz(((((ks << 2) | rb) << 6) | lane) << 4);
                bf16x8 ah = ldfrag((const char*)sP0 + ab);
                bf16x8 al = ldfrag((const char*)sP1 + ab);
                accl[rl] = __builtin_amdgcn_mfma_f32_16x16x32_bf16(ah, BLh[ks], accl[rl], 0, 0, 0);
                accl[rl] = __builtin_amdgcn_mfma_f32_16x16x32_bf16(ah, BLl[ks], accl[rl], 0, 0, 0);
                accl[rl] = __builtin_amdgcn_mfma_f32_16x16x32_bf16(al, BLh[ks], accl[rl], 0, 0, 0);
                accr[rl] = __builtin_amdgcn_mfma_f32_16x16x32_bf16(ah, BRh[ks], accr[rl], 0, 0, 0);
                accr[rl] = __builtin_amdgcn_mfma_f32_16x16x32_bf16(ah, BRl[ks], accr[rl], 0, 0, 0);
                accr[rl] = __builtin_amdgcn_mfma_f32_16x16x32_bf16(al, BRh[ks], accr[rl], 0, 0, 0);
            }
        }
#pragma unroll
        for (int rl = 0; rl < 2; ++rl) {
            int rb = (rbh << 1) | rl;
#pragma unroll
            for (int reg = 0; reg < 4; ++reg) {
                int row = (rb << 4) + r0 + reg;
                int n = n0t + row;
                if (n < NN) {
                    size_t off = ((size_t)n << 6) + col;
                    gout[off] = bfhi(accl[rl][reg]);
                    rA[off]   = accr[rl][reg] + bj;
                }
            }
        }
    }
}

// ============ FUSED final gather (layer 2) + global mean pool accumulate ============
__global__ void __launch_bounds__(256) k_gpool(const uint4* __restrict__ g4,
                                               const float* __restrict__ rA,
                                               const int* __restrict__ cnt,
                                               const int* __restrict__ ell,
                                               const int* __restrict__ batch,
                                               float* __restrict__ pool,
                                               float* __restrict__ cntg) {
    int lane = threadIdx.x & 63;
    int o    = lane >> 3;
    int c8   = lane & 7;
    int wv = __builtin_amdgcn_readfirstlane((int)((blockIdx.x * 256 + threadIdx.x) >> 6));
    int nw = (gridDim.x * 256) >> 6;
    for (int p = wv; p < NN / 8; p += nw) {
        int myn = 8 * p + o;
        int d   = cnt[myn];
        int dc  = min(d, MAXD);
        int dm  = max(dc, __shfl_xor(dc, 8));
        dm      = max(dm, __shfl_xor(dm, 16));
        dm      = max(dm, __shfl_xor(dm, 32));
        int iters = (dm + 7) & ~7;
        const int* er = ell + ((size_t)myn << 6) + (c8 << 3);
        int4 l0 = *(const int4*)er;
        int4 l1 = *(const int4*)(er + 4);
        float a0=0.f,a1=0.f,a2=0.f,a3=0.f,a4=0.f,a5=0.f,a6=0.f,a7=0.f;
        for (int j0 = 0; j0 < iters; j0 += 8) {
            int sl = (o << 3) | (j0 >> 3);
            int i0 = __shfl(l0.x, sl);
            int i1 = __shfl(l0.y, sl);
            int i2 = __shfl(l0.z, sl);
            int i3 = __shfl(l0.w, sl);
            int i4 = __shfl(l1.x, sl);
            int i5 = __shfl(l1.y, sl);
            int i6 = __shfl(l1.z, sl);
            int i7 = __shfl(l1.w, sl);
            i0 = (j0 + 0 < d) ? i0 : NN;
            i1 = (j0 + 1 < d) ? i1 : NN;
            i2 = (j0 + 2 < d) ? i2 : NN;
            i3 = (j0 + 3 < d) ? i3 : NN;
            i4 = (j0 + 4 < d) ? i4 : NN;
            i5 = (j0 + 5 < d) ? i5 : NN;
            i6 = (j0 + 6 < d) ? i6 : NN;
            i7 = (j0 + 7 < d) ? i7 : NN;
            uint4 u0 = g4[(size_t)i0 * 8 + c8];
            uint4 u1 = g4[(size_t)i1 * 8 + c8];
            uint4 u2 = g4[(size_t)i2 * 8 + c8];
            uint4 u3 = g4[(size_t)i3 * 8 + c8];
            uint4 u4 = g4[(size_t)i4 * 8 + c8];
            uint4 u5 = g4[(size_t)i5 * 8 + c8];
            uint4 u6 = g4[(size_t)i6 * 8 + c8];
            uint4 u7 = g4[(size_t)i7 * 8 + c8];
            ACCU(u0); ACCU(u1); ACCU(u2); ACCU(u3);
            ACCU(u4); ACCU(u5); ACCU(u6); ACCU(u7);
        }
        float inv = 1.0f / fmaxf((float)d, 1.0f);
        const float4* rp = (const float4*)(rA + ((size_t)myn << 6) + (c8 << 3));
        float4 rv0 = rp[0], rv1 = rp[1];
        float v0 = fmaxf(fmaf(a0, inv, rv0.x), 0.0f);
        float v1 = fmaxf(fmaf(a1, inv, rv0.y), 0.0f);
        float v2 = fmaxf(fmaf(a2, inv, rv0.z), 0.0f);
        float v3 = fmaxf(fmaf(a3, inv, rv0.w), 0.0f);
        float v4 = fmaxf(fmaf(a4, inv, rv1.x), 0.0f);
        float v5 = fmaxf(fmaf(a5, inv, rv1.y), 0.0f);
        float v6 = fmaxf(fmaf(a6, inv, rv1.z), 0.0f);
        float v7 = fmaxf(fmaf(a7, inv, rv1.w), 0.0f);
        int b  = batch[myn];
        int b0 = __shfl(b, c8);            // o=0's batch id (wave-uniform per c8 group)
        if (__all(b == b0)) {
            // tree-sum over the 8 nodes (lanes differing in bits 3..5)
#pragma unroll
            for (int m = 8; m <= 32; m <<= 1) {
                v0 += __shfl_xor(v0, m); v1 += __shfl_xor(v1, m);
                v2 += __shfl_xor(v2, m); v3 += __shfl_xor(v3, m);
                v4 += __shfl_xor(v4, m); v5 += __shfl_xor(v5, m);
                v6 += __shfl_xor(v6, m); v7 += __shfl_xor(v7, m);
            }
            if (o == 0) {
                float* pb = pool + ((size_t)b0 << 6) + (c8 << 3);
                atomicAdd(pb + 0, v0); atomicAdd(pb + 1, v1);
                atomicAdd(pb + 2, v2); atomicAdd(pb + 3, v3);
                atomicAdd(pb + 4, v4); atomicAdd(pb + 5, v5);
                atomicAdd(pb + 6, v6); atomicAdd(pb + 7, v7);
                if (c8 == 0) atomicAdd(&cntg[b0], 8.0f);
            }
        } else {
            float* pb = pool + ((size_t)b << 6) + (c8 << 3);
            atomicAdd(pb + 0, v0); atomicAdd(pb + 1, v1);
            atomicAdd(pb + 2, v2); atomicAdd(pb + 3, v3);
            atomicAdd(pb + 4, v4); atomicAdd(pb + 5, v5);
            atomicAdd(pb + 6, v6); atomicAdd(pb + 7, v7);
            if (c8 == 0) atomicAdd(&cntg[b], 1.0f);
        }
    }
}

// ============ output GEMM ============
__global__ void __launch_bounds__(256) k_out(const float* __restrict__ pool,
                                             const float* __restrict__ cntg,
                                             const float* __restrict__ W1,
                                             const float* __restrict__ b1,
                                             float* __restrict__ out) {
    __shared__ float sW[64 * 64];
    for (int i = threadIdx.x; i < 64 * 64; i += 256) sW[i] = W1[i];
    __syncthreads();
    int lane = threadIdx.x & 63;
    int wid  = (blockIdx.x * 256 + threadIdx.x) >> 6;
    int nw   = (gridDim.x * 256) >> 6;
    for (int gidx = wid; gidx < NG; gidx += nw) {
        float ic = 1.0f / fmaxf(cntg[gidx], 1.0f);
        float acc = 0.0f;
#pragma unroll
        for (int k = 0; k < 64; ++k)
            acc = fmaf(pool[(size_t)gidx * 64 + k], sW[k * 64 + lane], acc);
        out[(size_t)gidx * 64 + lane] = fmaf(acc, ic, b1[lane]);
    }
}

extern "C" void kernel_launch(void* const* d_in, const int* in_sizes, int n_in,
                              void* d_out, int out_size, void* d_ws, size_t ws_size,
                              hipStream_t stream) {
    const float* x     = (const float*)d_in[0];
    const int*   ei    = (const int*)d_in[1];   // [2,E]
    const int*   batch = (const int*)d_in[3];
    const float* W0    = (const float*)d_in[4];
    const float* b0    = (const float*)d_in[5];
    const float* Wl    = (const float*)d_in[6];
    const float* bl    = (const float*)d_in[7];
    const float* Wr    = (const float*)d_in[8];
    const float* W1    = (const float*)d_in[9];
    const float* b1    = (const float*)d_in[10];
    float* out = (float*)d_out;

    char* ws = (char*)d_ws;
    size_t off = 0;
    auto alloc = [&](size_t bytes) -> void* {
        void* p = ws + off;
        off += (bytes + 255) & ~(size_t)255;
        return p;
    };
    float*          A  = (float*)alloc((size_t)NN * 64 * 4);              // h / r (in-place)
    unsigned short* G0 = (unsigned short*)alloc((size_t)NN * 128);        // g ping
    size_t z1start = off;
    (void)alloc(256);                                                     // G0 zero row (row NN)
    unsigned short* G1 = (unsigned short*)alloc((size_t)NN * 128);        // g pong
    size_t z2start = off;
    (void)alloc(256);                                                     // G1 zero row (row NN)
    int*   cursor = (int*)alloc((size_t)NBUK * 4);
    float* pool   = (float*)alloc((size_t)NG * 64 * 4);
    float* cntg   = (float*)alloc((size_t)NG * 4);
    size_t z2len = off - z2start;
    int*          ell    = (int*)alloc((size_t)NN * MAXD * 4);            // ELL (tails garbage, masked)
    unsigned int* bucket = (unsigned int*)alloc((size_t)NBUK * BCAP * 4);
    int*          cnt    = (int*)alloc((size_t)NN * 4);                   // fully written by k_mid

    const int* src = ei;
    const int* dst = ei + NE;

    hipMemsetAsync(ws + z1start, 0, 256, stream);          // G0 zero row
    hipMemsetAsync(ws + z2start, 0, z2len, stream);        // G1 zero row + cursor + pool + cntg

    // phase-1 binning || input projection (MFMA)
    k_front<<<NBUK + GB, 512, 0, stream>>>(src, dst, cursor, bucket, x, W0, b0, A);
    // phase-2 ELL build (no sentinel init) || gemmLR layer 0 -> G0, r0
    k_mid<<<NBUK + MGB, 256, 0, stream>>>(bucket, cursor, cnt, ell, A,
                                          (__hip_bfloat16*)G0, Wl, bl, Wr);
    // fused gather0 + gemmLR1: G0 -> G1
    k_gg<<<FB, 512, 0, stream>>>((const uint4*)G0, A, G1, cnt, ell,
                                 Wl + (size_t)1 * 64 * 64, bl + 64, Wr + (size_t)1 * 64 * 64);
    // fused gather1 + gemmLR2: G1 -> G0
    k_gg<<<FB, 512, 0, stream>>>((const uint4*)G1, A, G0, cnt, ell,
                                 Wl + (size_t)2 * 64 * 64, bl + 128, Wr + (size_t)2 * 64 * 64);
    // fused final gather (layer 2) + mean-pool accumulate
    k_gpool<<<3125, 256, 0, stream>>>((const uint4*)G0, A, cnt, ell, batch, pool, cntg);

    k_out<<<128, 256, 0, stream>>>(pool, cntg, W1, b1, out);
}

// Round 10
// 371.814 us; speedup vs baseline: 1.1635x; 1.0420x over previous
//
#include <hip/hip_runtime.h>
#include <hip/hip_bf16.h>

#define NN 100000
#define NE 1600000
#define DIN 128
#define NG 512
#define MAXD 64
#define NBUK 391               // dst>>8 buckets (256 nodes each)
#define BCAP 5120              // mean 4092, +16 sigma
#define CHUNK ((NE + NBUK - 1) / NBUK)
#define NTILE ((NN + 63) >> 6)  // 64-node tiles

typedef __attribute__((ext_vector_type(8))) __bf16 bf16x8;
typedef __attribute__((ext_vector_type(4))) float f32x4;

static __device__ __forceinline__ unsigned short bfhi(float f) {
    __hip_bfloat16 h = __float2bfloat16(f);
    return *reinterpret_cast<unsigned short*>(&h);
}
static __device__ __forceinline__ float bf2f(unsigned short u) {
    unsigned v = (unsigned)u << 16;
    return __uint_as_float(v);
}
static __device__ __forceinline__ bf16x8 ldfrag(const void* p) {
    bf16x8 r;
    __builtin_memcpy(&r, p, 16);
    return r;
}
// LDS frag-bank swizzle: XOR bits>=4 only (8B writes / 16B reads stay aligned).
static __device__ __forceinline__ int swz(int a) {
    return a ^ (((a >> 8) & 3) << 5) ^ (((a >> 12) & 3) << 4);
}

// Fragment addressing (mfma_f32_16x16x32_bf16):
//  A: lane l holds A[R0 + (l&15)][32*ks + 8*(l>>4) + j], j=0..7
//  B: lane l holds B[32*ks + 8*(l>>4) + j][C0 + (l&15)]
//  C/D: col = C0 + (lane&15), row = R0 + (lane>>4)*4 + reg   [verified layout]
// LDS frag order: byte = swz( (((slot*64 + lane)*8 + j) * 2) ), slot = ks*4 + rb/cb.
// GRID SIZING [round-8 lesson]: per-block W-prepack is the dominant fixed cost;
// blocks must process >=3 tiles each (FB=512, GB=256). Larger grids regress.

// ============ fused: phase-1 binning (blocks 0..NBUK) ||
//              input GEMM + gemmLR layer 0 chained per tile (rest) ============
// GEMM blocks: x-tile -> h (regs, GEMM1 vs W0) -> restage h as A-frags (LDS scatter)
// -> GEMM2 (Wl0/Wr0) -> write G0, r0. h NEVER touches HBM.
#define GB 256
__global__ void __launch_bounds__(512) k_front(const int* __restrict__ src,
                                               const int* __restrict__ dst,
                                               int* __restrict__ cursor,
                                               unsigned int* __restrict__ bucket,
                                               const float* __restrict__ x,
                                               const float* __restrict__ W0,
                                               const float* __restrict__ b0,
                                               const float* __restrict__ Wl0,
                                               const float* __restrict__ bl0,
                                               const float* __restrict__ Wr0,
                                               unsigned short* __restrict__ gout,
                                               float* __restrict__ rA) {
    __shared__ unsigned short sW0[2 * 8192];  // W0 frags, persistent (32 KB)
    __shared__ unsigned short sS2[2 * 8192];  // x-tile staging / h-frag staging (32 KB)
    __shared__ int lcnt[NBUK];
    __shared__ int lbase[NBUK];
    if (blockIdx.x < NBUK) {
        for (int i = threadIdx.x; i < NBUK; i += 512) lcnt[i] = 0;
        __syncthreads();
        int e0 = blockIdx.x * CHUNK;
        int e1 = min(e0 + CHUNK, NE);
        for (int e = e0 + (int)threadIdx.x; e < e1; e += 512)
            atomicAdd(&lcnt[dst[e] >> 8], 1);
        __syncthreads();
        for (int i = threadIdx.x; i < NBUK; i += 512) {
            int c = lcnt[i];
            lbase[i] = c ? atomicAdd(&cursor[i], c) : 0;
            lcnt[i] = 0;
        }
        __syncthreads();
        for (int e = e0 + (int)threadIdx.x; e < e1; e += 512) {
            int d = dst[e];
            int s = src[e];
            int bk = d >> 8;
            int pos = lbase[bk] + atomicAdd(&lcnt[bk], 1);
            if (pos < BCAP)
                bucket[(size_t)bk * BCAP + pos] = ((unsigned)s << 8) | (unsigned)(d & 255);
        }
    } else {
        int tid = (int)threadIdx.x;
        unsigned short* w0h = sW0;
        unsigned short* w0l = sW0 + 8192;
        unsigned short* sP0 = sS2;            // x hi plane (16 KB)
        unsigned short* sP1 = sS2 + 8192;     // x lo plane
        unsigned short* hP0 = sS2;            // h hi plane (8 KB, reuses x buffer)
        unsigned short* hP1 = sS2 + 4096;     // h lo plane
        // prepack W0 into LDS frag order (persistent)
        for (int i = tid; i < 8192; i += 512) {
            int k = i >> 6, c = i & 63;
            int slot = ((k >> 5) << 2) | (c >> 4);
            int ln   = (((k >> 3) & 3) << 4) | (c & 15);
            int ba   = swz((((((slot << 6) | ln) << 3) | (k & 7)) << 1));
            float w = W0[i];
            unsigned short hh = bfhi(w);
            *(unsigned short*)((char*)w0h + ba) = hh;
            *(unsigned short*)((char*)w0l + ba) = bfhi(w - bf2f(hh));
        }
        int lane = tid & 63;
        int wv   = tid >> 6;                  // 8 waves
        int cb   = wv & 3;
        int rbh  = wv >> 2;
        int col  = (cb << 4) | (lane & 15);
        float bj  = b0[col];
        float bj2 = bl0[col];
        int r0   = (lane >> 4) << 2;
        bf16x8 BLh[2], BLl[2], BRh[2], BRl[2];
        // prepack Wl0 -> frags -> regs (transient in sS2)
        for (int i = tid; i < 4096; i += 512) {
            int k = i >> 6, c = i & 63;
            int slot = ((k >> 5) << 2) | (c >> 4);
            int ln   = (((k >> 3) & 3) << 4) | (c & 15);
            int ba   = swz((((((slot << 6) | ln) << 3) | (k & 7)) << 1));
            float w = Wl0[i];
            unsigned short hh = bfhi(w);
            *(unsigned short*)((char*)hP0 + ba) = hh;
            *(unsigned short*)((char*)hP1 + ba) = bfhi(w - bf2f(hh));
        }
        __syncthreads();
#pragma unroll
        for (int ks = 0; ks < 2; ++ks) {
            int bb = swz(((((ks << 2) | cb) << 6) | lane) << 4);
            BLh[ks] = ldfrag((const char*)hP0 + bb);
            BLl[ks] = ldfrag((const char*)hP1 + bb);
        }
        __syncthreads();
        // prepack Wr0 -> frags -> regs
        for (int i = tid; i < 4096; i += 512) {
            int k = i >> 6, c = i & 63;
            int slot = ((k >> 5) << 2) | (c >> 4);
            int ln   = (((k >> 3) & 3) << 4) | (c & 15);
            int ba   = swz((((((slot << 6) | ln) << 3) | (k & 7)) << 1));
            float w = Wr0[i];
            unsigned short hh = bfhi(w);
            *(unsigned short*)((char*)hP0 + ba) = hh;
            *(unsigned short*)((char*)hP1 + ba) = bfhi(w - bf2f(hh));
        }
        __syncthreads();
#pragma unroll
        for (int ks = 0; ks < 2; ++ks) {
            int bb = swz(((((ks << 2) | cb) << 6) | lane) << 4);
            BRh[ks] = ldfrag((const char*)hP0 + bb);
            BRl[ks] = ldfrag((const char*)hP1 + bb);
        }
        for (int t = blockIdx.x - NBUK; t < NTILE; t += GB) {
            int n0 = t << 6;
            __syncthreads();                  // prev GEMM2 reads done / BR frag reads done
            // ---- stage 64x128 x-tile -> hi/lo frags ----
#pragma unroll
            for (int i = 0; i < 4; ++i) {
                int tau = tid + (i << 9);
                int r = tau >> 5, kq = tau & 31;
                int n = n0 + r;
                float4 v = make_float4(0.f, 0.f, 0.f, 0.f);
                if (n < NN) v = *(const float4*)(x + ((size_t)n << 7) + (kq << 2));
                int k0   = kq << 2;
                int slot = ((k0 >> 5) << 2) | (r >> 4);
                int ln   = (((k0 >> 3) & 3) << 4) | (r & 15);
                int ba   = swz((((((slot << 6) | ln) << 3) | (k0 & 7)) << 1));
                unsigned short h0 = bfhi(v.x), h1 = bfhi(v.y),
                               h2 = bfhi(v.z), h3 = bfhi(v.w);
                *(ushort4*)((char*)sP0 + ba) = make_ushort4(h0, h1, h2, h3);
                *(ushort4*)((char*)sP1 + ba) = make_ushort4(
                    bfhi(v.x - bf2f(h0)), bfhi(v.y - bf2f(h1)),
                    bfhi(v.z - bf2f(h2)), bfhi(v.w - bf2f(h3)));
            }
            __syncthreads();
            // ---- GEMM1: h = relu(x @ W0 + b0), W0 B-frags from LDS ----
            f32x4 acc[2] = {{0.f,0.f,0.f,0.f},{0.f,0.f,0.f,0.f}};
#pragma unroll
            for (int ks = 0; ks < 4; ++ks) {
                int bb = swz(((((ks << 2) | cb) << 6) | lane) << 4);
                bf16x8 bh  = ldfrag((const char*)w0h + bb);
                bf16x8 bl_ = ldfrag((const char*)w0l + bb);
#pragma unroll
                for (int rl = 0; rl < 2; ++rl) {
                    int rb = (rbh << 1) | rl;
                    int ab = swz(((((ks << 2) | rb) << 6) | lane) << 4);
                    bf16x8 ah = ldfrag((const char*)sP0 + ab);
                    bf16x8 al = ldfrag((const char*)sP1 + ab);
                    acc[rl] = __builtin_amdgcn_mfma_f32_16x16x32_bf16(ah, bh,  acc[rl], 0, 0, 0);
                    acc[rl] = __builtin_amdgcn_mfma_f32_16x16x32_bf16(ah, bl_, acc[rl], 0, 0, 0);
                    acc[rl] = __builtin_amdgcn_mfma_f32_16x16x32_bf16(al, bh,  acc[rl], 0, 0, 0);
                }
            }
            __syncthreads();                  // GEMM1's sP reads done before h overwrite
            // ---- restage h (C/D layout regs) -> A-frags in LDS (2B scatter) ----
#pragma unroll
            for (int rl = 0; rl < 2; ++rl) {
                int rb = (rbh << 1) | rl;
#pragma unroll
                for (int reg = 0; reg < 4; ++reg) {
                    int row = (rb << 4) + r0 + reg;
                    float v = fmaxf(acc[rl][reg] + bj, 0.f);
                    int slot = ((col >> 5) << 2) | rb;
                    int ln   = (((col >> 3) & 3) << 4) | (row & 15);
                    int ba   = swz((((((slot << 6) | ln) << 3) | (col & 7)) << 1));
                    unsigned short hh = bfhi(v);
                    *(unsigned short*)((char*)hP0 + ba) = hh;
                    *(unsigned short*)((char*)hP1 + ba) = bfhi(v - bf2f(hh));
                }
            }
            __syncthreads();
            // ---- GEMM2: g0 = h@Wl0 ; r0 = h@Wr0 + bl0 ----
            f32x4 accl[2] = {{0.f,0.f,0.f,0.f},{0.f,0.f,0.f,0.f}};
            f32x4 accr[2] = {{0.f,0.f,0.f,0.f},{0.f,0.f,0.f,0.f}};
#pragma unroll
            for (int ks = 0; ks < 2; ++ks) {
#pragma unroll
                for (int rl = 0; rl < 2; ++rl) {
                    int rb = (rbh << 1) | rl;
                    int ab = swz(((((ks << 2) | rb) << 6) | lane) << 4);
                    bf16x8 ah = ldfrag((const char*)hP0 + ab);
                    bf16x8 al = ldfrag((const char*)hP1 + ab);
                    accl[rl] = __builtin_amdgcn_mfma_f32_16x16x32_bf16(ah, BLh[ks], accl[rl], 0, 0, 0);
                    accl[rl] = __builtin_amdgcn_mfma_f32_16x16x32_bf16(ah, BLl[ks], accl[rl], 0, 0, 0);
                    accl[rl] = __builtin_amdgcn_mfma_f32_16x16x32_bf16(al, BLh[ks], accl[rl], 0, 0, 0);
                    accr[rl] = __builtin_amdgcn_mfma_f32_16x16x32_bf16(ah, BRh[ks], accr[rl], 0, 0, 0);
                    accr[rl] = __builtin_amdgcn_mfma_f32_16x16x32_bf16(ah, BRl[ks], accr[rl], 0, 0, 0);
                    accr[rl] = __builtin_amdgcn_mfma_f32_16x16x32_bf16(al, BRh[ks], accr[rl], 0, 0, 0);
                }
            }
#pragma unroll
            for (int rl = 0; rl < 2; ++rl) {
                int rb = (rbh << 1) | rl;
#pragma unroll
                for (int reg = 0; reg < 4; ++reg) {
                    int row = (rb << 4) + r0 + reg;
                    int n = n0 + row;
                    if (n < NN) {
                        size_t off = ((size_t)n << 6) + col;
                        gout[off] = bfhi(accl[rl][reg]);
                        rA[off]   = accr[rl][reg] + bj2;
                    }
                }
            }
        }
    }
}

// ============ phase-2 ELL build only (no sentinel init; gather masks tails) ============
__global__ void __launch_bounds__(256) k_mide(const unsigned int* __restrict__ bucket,
                                              const int* __restrict__ cursor,
                                              int* __restrict__ cnt,
                                              int* __restrict__ ell) {
    __shared__ int lc[256];
    lc[threadIdx.x] = 0;
    int b = blockIdx.x;
    __syncthreads();
    int m = min(cursor[b], BCAP);
    const unsigned int* bp = bucket + (size_t)b * BCAP;
    for (int i = threadIdx.x; i < m; i += 256) {
        unsigned v = bp[i];
        int dlo = (int)(v & 255u);
        int s   = (int)(v >> 8);
        int p   = atomicAdd(&lc[dlo], 1);
        if (p < MAXD)
            ell[(((size_t)b << 8) + dlo) * MAXD + p] = s;
    }
    __syncthreads();
    int n = (b << 8) + (int)threadIdx.x;
    if (n < NN) cnt[n] = lc[threadIdx.x];
}

#define ACCU(U) { \
    a0 += __uint_as_float((U).x << 16); a1 += __uint_as_float((U).x & 0xffff0000u); \
    a2 += __uint_as_float((U).y << 16); a3 += __uint_as_float((U).y & 0xffff0000u); \
    a4 += __uint_as_float((U).z << 16); a5 += __uint_as_float((U).z & 0xffff0000u); \
    a6 += __uint_as_float((U).w << 16); a7 += __uint_as_float((U).w & 0xffff0000u); }

// ============ FUSED gather(l) + gemmLR(l+1): one 64-node tile per block-iteration ====
#define FB 512
__global__ void __launch_bounds__(512) k_gg(const uint4* __restrict__ gin,
                                            float* __restrict__ rA,
                                            unsigned short* __restrict__ gout,
                                            const int* __restrict__ cnt,
                                            const int* __restrict__ ell,
                                            const float* __restrict__ Wl,
                                            const float* __restrict__ bl,
                                            const float* __restrict__ Wr) {
    __shared__ unsigned short sS[2 * 4096];
    unsigned short* sP0 = sS;
    unsigned short* sP1 = sS + 4096;
    int tid = (int)threadIdx.x;
    int lane = tid & 63;
    int w    = tid >> 6;                 // 8 waves
    int cb   = w & 3;
    int rbh  = w >> 2;
    bf16x8 BLh[2], BLl[2], BRh[2], BRl[2];
    for (int i = tid; i < 4096; i += 512) {
        int k = i >> 6, c = i & 63;
        int slot = ((k >> 5) << 2) | (c >> 4);
        int ln   = (((k >> 3) & 3) << 4) | (c & 15);
        int ba   = swz((((((slot << 6) | ln) << 3) | (k & 7)) << 1));
        float wv_ = Wl[i];
        unsigned short hh = bfhi(wv_);
        *(unsigned short*)((char*)sP0 + ba) = hh;
        *(unsigned short*)((char*)sP1 + ba) = bfhi(wv_ - bf2f(hh));
    }
    __syncthreads();
#pragma unroll
    for (int ks = 0; ks < 2; ++ks) {
        int bb = swz(((((ks << 2) | cb) << 6) | lane) << 4);
        BLh[ks] = ldfrag((const char*)sP0 + bb);
        BLl[ks] = ldfrag((const char*)sP1 + bb);
    }
    __syncthreads();
    for (int i = tid; i < 4096; i += 512) {
        int k = i >> 6, c = i & 63;
        int slot = ((k >> 5) << 2) | (c >> 4);
        int ln   = (((k >> 3) & 3) << 4) | (c & 15);
        int ba   = swz((((((slot << 6) | ln) << 3) | (k & 7)) << 1));
        float wv_ = Wr[i];
        unsigned short hh = bfhi(wv_);
        *(unsigned short*)((char*)sP0 + ba) = hh;
        *(unsigned short*)((char*)sP1 + ba) = bfhi(wv_ - bf2f(hh));
    }
    __syncthreads();
#pragma unroll
    for (int ks = 0; ks < 2; ++ks) {
        int bb = swz(((((ks << 2) | cb) << 6) | lane) << 4);
        BRh[ks] = ldfrag((const char*)sP0 + bb);
        BRl[ks] = ldfrag((const char*)sP1 + bb);
    }
    int col = (cb << 4) | (lane & 15);
    float bj = bl[col];
    int r0  = (lane >> 4) << 2;
    int o   = lane >> 3;
    int c8  = lane & 7;
    for (int t = blockIdx.x; t < NTILE; t += FB) {
        int n0t = t << 6;
        int myn = n0t + (w << 3) + o;
        int d = (myn < NN) ? cnt[myn] : 0;
        int dc = min(d, MAXD);
        int dm = max(dc, __shfl_xor(dc, 8));
        dm     = max(dm, __shfl_xor(dm, 16));
        dm     = max(dm, __shfl_xor(dm, 32));
        int iters = (dm + 7) & ~7;
        const int* er = ell + ((size_t)min(myn, NN - 1) << 6) + (c8 << 3);
        int4 l0 = *(const int4*)er;
        int4 l1 = *(const int4*)(er + 4);
        float a0=0.f,a1=0.f,a2=0.f,a3=0.f,a4=0.f,a5=0.f,a6=0.f,a7=0.f;
        for (int j0 = 0; j0 < iters; j0 += 8) {
            int sl = (o << 3) | (j0 >> 3);
            int i0 = __shfl(l0.x, sl);
            int i1 = __shfl(l0.y, sl);
            int i2 = __shfl(l0.z, sl);
            int i3 = __shfl(l0.w, sl);
            int i4 = __shfl(l1.x, sl);
            int i5 = __shfl(l1.y, sl);
            int i6 = __shfl(l1.z, sl);
            int i7 = __shfl(l1.w, sl);
            i0 = (j0 + 0 < d) ? i0 : NN;
            i1 = (j0 + 1 < d) ? i1 : NN;
            i2 = (j0 + 2 < d) ? i2 : NN;
            i3 = (j0 + 3 < d) ? i3 : NN;
            i4 = (j0 + 4 < d) ? i4 : NN;
            i5 = (j0 + 5 < d) ? i5 : NN;
            i6 = (j0 + 6 < d) ? i6 : NN;
            i7 = (j0 + 7 < d) ? i7 : NN;
            uint4 u0 = gin[(size_t)i0 * 8 + c8];
            uint4 u1 = gin[(size_t)i1 * 8 + c8];
            uint4 u2 = gin[(size_t)i2 * 8 + c8];
            uint4 u3 = gin[(size_t)i3 * 8 + c8];
            uint4 u4 = gin[(size_t)i4 * 8 + c8];
            uint4 u5 = gin[(size_t)i5 * 8 + c8];
            uint4 u6 = gin[(size_t)i6 * 8 + c8];
            uint4 u7 = gin[(size_t)i7 * 8 + c8];
            ACCU(u0); ACCU(u1); ACCU(u2); ACCU(u3);
            ACCU(u4); ACCU(u5); ACCU(u6); ACCU(u7);
        }
        float4 rv0 = make_float4(0.f,0.f,0.f,0.f), rv1 = rv0;
        if (myn < NN) {
            float inv = 1.0f / fmaxf((float)d, 1.0f);
            const float4* rp = (const float4*)(rA + ((size_t)myn << 6) + (c8 << 3));
            rv0 = rp[0]; rv1 = rp[1];
            rv0.x = fmaxf(fmaf(a0, inv, rv0.x), 0.0f);
            rv0.y = fmaxf(fmaf(a1, inv, rv0.y), 0.0f);
            rv0.z = fmaxf(fmaf(a2, inv, rv0.z), 0.0f);
            rv0.w = fmaxf(fmaf(a3, inv, rv0.w), 0.0f);
            rv1.x = fmaxf(fmaf(a4, inv, rv1.x), 0.0f);
            rv1.y = fmaxf(fmaf(a5, inv, rv1.y), 0.0f);
            rv1.z = fmaxf(fmaf(a6, inv, rv1.z), 0.0f);
            rv1.w = fmaxf(fmaf(a7, inv, rv1.w), 0.0f);
        }
        __syncthreads();
        {
            int rr = (w << 3) + o;
#pragma unroll
            for (int half = 0; half < 2; ++half) {
                float4 v = half ? rv1 : rv0;
                int k0 = (c8 << 3) + (half << 2);
                int slot = ((k0 >> 5) << 2) | (rr >> 4);
                int ln   = (((k0 >> 3) & 3) << 4) | (rr & 15);
                int ba   = swz((((((slot << 6) | ln) << 3) | (k0 & 7)) << 1));
                unsigned short h0 = bfhi(v.x), h1 = bfhi(v.y),
                               h2 = bfhi(v.z), h3 = bfhi(v.w);
                *(ushort4*)((char*)sP0 + ba) = make_ushort4(h0, h1, h2, h3);
                *(ushort4*)((char*)sP1 + ba) = make_ushort4(
                    bfhi(v.x - bf2f(h0)), bfhi(v.y - bf2f(h1)),
                    bfhi(v.z - bf2f(h2)), bfhi(v.w - bf2f(h3)));
            }
        }
        __syncthreads();
        f32x4 accl[2] = {{0.f,0.f,0.f,0.f},{0.f,0.f,0.f,0.f}};
        f32x4 accr[2] = {{0.f,0.f,0.f,0.f},{0.f,0.f,0.f,0.f}};
#pragma unroll
        for (int ks = 0; ks < 2; ++ks) {
#pragma unroll
            for (int rl = 0; rl < 2; ++rl) {
                int rb = (rbh << 1) | rl;
                int ab = swz(((((ks << 2) | rb) << 6) | lane) << 4);
                bf16x8 ah = ldfrag((const char*)sP0 + ab);
                bf16x8 al = ldfrag((const char*)sP1 + ab);
                accl[rl] = __builtin_amdgcn_mfma_f32_16x16x32_bf16(ah, BLh[ks], accl[rl], 0, 0, 0);
                accl[rl] = __builtin_amdgcn_mfma_f32_16x16x32_bf16(ah, BLl[ks], accl[rl], 0, 0, 0);
                accl[rl] = __builtin_amdgcn_mfma_f32_16x16x32_bf16(al, BLh[ks], accl[rl], 0, 0, 0);
                accr[rl] = __builtin_amdgcn_mfma_f32_16x16x32_bf16(ah, BRh[ks], accr[rl], 0, 0, 0);
                accr[rl] = __builtin_amdgcn_mfma_f32_16x16x32_bf16(ah, BRl[ks], accr[rl], 0, 0, 0);
                accr[rl] = __builtin_amdgcn_mfma_f32_16x16x32_bf16(al, BRh[ks], accr[rl], 0, 0, 0);
            }
        }
#pragma unroll
        for (int rl = 0; rl < 2; ++rl) {
            int rb = (rbh << 1) | rl;
#pragma unroll
            for (int reg = 0; reg < 4; ++reg) {
                int row = (rb << 4) + r0 + reg;
                int n = n0t + row;
                if (n < NN) {
                    size_t off = ((size_t)n << 6) + col;
                    gout[off] = bfhi(accl[rl][reg]);
                    rA[off]   = accr[rl][reg] + bj;
                }
            }
        }
    }
}

// ============ FUSED final gather (layer 2) + global mean pool accumulate ============
__global__ void __launch_bounds__(256) k_gpool(const uint4* __restrict__ g4,
                                               const float* __restrict__ rA,
                                               const int* __restrict__ cnt,
                                               const int* __restrict__ ell,
                                               const int* __restrict__ batch,
                                               float* __restrict__ pool,
                                               float* __restrict__ cntg) {
    int lane = threadIdx.x & 63;
    int o    = lane >> 3;
    int c8   = lane & 7;
    int wv = __builtin_amdgcn_readfirstlane((int)((blockIdx.x * 256 + threadIdx.x) >> 6));
    int nw = (gridDim.x * 256) >> 6;
    for (int p = wv; p < NN / 8; p += nw) {
        int myn = 8 * p + o;
        int d   = cnt[myn];
        int dc  = min(d, MAXD);
        int dm  = max(dc, __shfl_xor(dc, 8));
        dm      = max(dm, __shfl_xor(dm, 16));
        dm      = max(dm, __shfl_xor(dm, 32));
        int iters = (dm + 7) & ~7;
        const int* er = ell + ((size_t)myn << 6) + (c8 << 3);
        int4 l0 = *(const int4*)er;
        int4 l1 = *(const int4*)(er + 4);
        float a0=0.f,a1=0.f,a2=0.f,a3=0.f,a4=0.f,a5=0.f,a6=0.f,a7=0.f;
        for (int j0 = 0; j0 < iters; j0 += 8) {
            int sl = (o << 3) | (j0 >> 3);
            int i0 = __shfl(l0.x, sl);
            int i1 = __shfl(l0.y, sl);
            int i2 = __shfl(l0.z, sl);
            int i3 = __shfl(l0.w, sl);
            int i4 = __shfl(l1.x, sl);
            int i5 = __shfl(l1.y, sl);
            int i6 = __shfl(l1.z, sl);
            int i7 = __shfl(l1.w, sl);
            i0 = (j0 + 0 < d) ? i0 : NN;
            i1 = (j0 + 1 < d) ? i1 : NN;
            i2 = (j0 + 2 < d) ? i2 : NN;
            i3 = (j0 + 3 < d) ? i3 : NN;
            i4 = (j0 + 4 < d) ? i4 : NN;
            i5 = (j0 + 5 < d) ? i5 : NN;
            i6 = (j0 + 6 < d) ? i6 : NN;
            i7 = (j0 + 7 < d) ? i7 : NN;
            uint4 u0 = g4[(size_t)i0 * 8 + c8];
            uint4 u1 = g4[(size_t)i1 * 8 + c8];
            uint4 u2 = g4[(size_t)i2 * 8 + c8];
            uint4 u3 = g4[(size_t)i3 * 8 + c8];
            uint4 u4 = g4[(size_t)i4 * 8 + c8];
            uint4 u5 = g4[(size_t)i5 * 8 + c8];
            uint4 u6 = g4[(size_t)i6 * 8 + c8];
            uint4 u7 = g4[(size_t)i7 * 8 + c8];
            ACCU(u0); ACCU(u1); ACCU(u2); ACCU(u3);
            ACCU(u4); ACCU(u5); ACCU(u6); ACCU(u7);
        }
        float inv = 1.0f / fmaxf((float)d, 1.0f);
        const float4* rp = (const float4*)(rA + ((size_t)myn << 6) + (c8 << 3));
        float4 rv0 = rp[0], rv1 = rp[1];
        float v0 = fmaxf(fmaf(a0, inv, rv0.x), 0.0f);
        float v1 = fmaxf(fmaf(a1, inv, rv0.y), 0.0f);
        float v2 = fmaxf(fmaf(a2, inv, rv0.z), 0.0f);
        float v3 = fmaxf(fmaf(a3, inv, rv0.w), 0.0f);
        float v4 = fmaxf(fmaf(a4, inv, rv1.x), 0.0f);
        float v5 = fmaxf(fmaf(a5, inv, rv1.y), 0.0f);
        float v6 = fmaxf(fmaf(a6, inv, rv1.z), 0.0f);
        float v7 = fmaxf(fmaf(a7, inv, rv1.w), 0.0f);
        int b  = batch[myn];
        int b0 = __shfl(b, c8);            // o=0's batch id (wave-uniform per c8 group)
        if (__all(b == b0)) {
#pragma unroll
            for (int m = 8; m <= 32; m <<= 1) {
                v0 += __shfl_xor(v0, m); v1 += __shfl_xor(v1, m);
                v2 += __shfl_xor(v2, m); v3 += __shfl_xor(v3, m);
                v4 += __shfl_xor(v4, m); v5 += __shfl_xor(v5, m);
                v6 += __shfl_xor(v6, m); v7 += __shfl_xor(v7, m);
            }
            if (o == 0) {
                float* pb = pool + ((size_t)b0 << 6) + (c8 << 3);
                atomicAdd(pb + 0, v0); atomicAdd(pb + 1, v1);
                atomicAdd(pb + 2, v2); atomicAdd(pb + 3, v3);
                atomicAdd(pb + 4, v4); atomicAdd(pb + 5, v5);
                atomicAdd(pb + 6, v6); atomicAdd(pb + 7, v7);
                if (c8 == 0) atomicAdd(&cntg[b0], 8.0f);
            }
        } else {
            float* pb = pool + ((size_t)b << 6) + (c8 << 3);
            atomicAdd(pb + 0, v0); atomicAdd(pb + 1, v1);
            atomicAdd(pb + 2, v2); atomicAdd(pb + 3, v3);
            atomicAdd(pb + 4, v4); atomicAdd(pb + 5, v5);
            atomicAdd(pb + 6, v6); atomicAdd(pb + 7, v7);
            if (c8 == 0) atomicAdd(&cntg[b], 1.0f);
        }
    }
}

// ============ output GEMM ============
__global__ void __launch_bounds__(256) k_out(const float* __restrict__ pool,
                                             const float* __restrict__ cntg,
                                             const float* __restrict__ W1,
                                             const float* __restrict__ b1,
                                             float* __restrict__ out) {
    __shared__ float sW[64 * 64];
    for (int i = threadIdx.x; i < 64 * 64; i += 256) sW[i] = W1[i];
    __syncthreads();
    int lane = threadIdx.x & 63;
    int wid  = (blockIdx.x * 256 + threadIdx.x) >> 6;
    int nw   = (gridDim.x * 256) >> 6;
    for (int gidx = wid; gidx < NG; gidx += nw) {
        float ic = 1.0f / fmaxf(cntg[gidx], 1.0f);
        float acc = 0.0f;
#pragma unroll
        for (int k = 0; k < 64; ++k)
            acc = fmaf(pool[(size_t)gidx * 64 + k], sW[k * 64 + lane], acc);
        out[(size_t)gidx * 64 + lane] = fmaf(acc, ic, b1[lane]);
    }
}

extern "C" void kernel_launch(void* const* d_in, const int* in_sizes, int n_in,
                              void* d_out, int out_size, void* d_ws, size_t ws_size,
                              hipStream_t stream) {
    const float* x     = (const float*)d_in[0];
    const int*   ei    = (const int*)d_in[1];   // [2,E]
    const int*   batch = (const int*)d_in[3];
    const float* W0    = (const float*)d_in[4];
    const float* b0    = (const float*)d_in[5];
    const float* Wl    = (const float*)d_in[6];
    const float* bl    = (const float*)d_in[7];
    const float* Wr    = (const float*)d_in[8];
    const float* W1    = (const float*)d_in[9];
    const float* b1    = (const float*)d_in[10];
    float* out = (float*)d_out;

    char* ws = (char*)d_ws;
    size_t off = 0;
    auto alloc = [&](size_t bytes) -> void* {
        void* p = ws + off;
        off += (bytes + 255) & ~(size_t)255;
        return p;
    };
    float*          A  = (float*)alloc((size_t)NN * 64 * 4);              // r (in-place)
    unsigned short* G0 = (unsigned short*)alloc((size_t)NN * 128);        // g ping
    size_t z1start = off;
    (void)alloc(256);                                                     // G0 zero row (row NN)
    unsigned short* G1 = (unsigned short*)alloc((size_t)NN * 128);        // g pong
    size_t z2start = off;
    (void)alloc(256);                                                     // G1 zero row (row NN)
    int*   cursor = (int*)alloc((size_t)NBUK * 4);
    float* pool   = (float*)alloc((size_t)NG * 64 * 4);
    float* cntg   = (float*)alloc((size_t)NG * 4);
    size_t z2len = off - z2start;
    int*          ell    = (int*)alloc((size_t)NN * MAXD * 4);            // ELL (tails garbage, masked)
    unsigned int* bucket = (unsigned int*)alloc((size_t)NBUK * BCAP * 4);
    int*          cnt    = (int*)alloc((size_t)NN * 4);                   // fully written by k_mide

    const int* src = ei;
    const int* dst = ei + NE;

    hipMemsetAsync(ws + z1start, 0, 256, stream);          // G0 zero row
    hipMemsetAsync(ws + z2start, 0, z2len, stream);        // G1 zero row + cursor + pool + cntg

    // phase-1 binning || x->h->gemmLR0 fused (MFMA) -> G0, r0. h never hits HBM.
    k_front<<<NBUK + GB, 512, 0, stream>>>(src, dst, cursor, bucket, x, W0, b0,
                                           Wl, bl, Wr, G0, A);
    // phase-2 ELL build only
    k_mide<<<NBUK, 256, 0, stream>>>(bucket, cursor, cnt, ell);
    // fused gather0 + gemmLR1: G0 -> G1
    k_gg<<<FB, 512, 0, stream>>>((const uint4*)G0, A, G1, cnt, ell,
                                 Wl + (size_t)1 * 64 * 64, bl + 64, Wr + (size_t)1 * 64 * 64);
    // fused gather1 + gemmLR2: G1 -> G0
    k_gg<<<FB, 512, 0, stream>>>((const uint4*)G1, A, G0, cnt, ell,
                                 Wl + (size_t)2 * 64 * 64, bl + 128, Wr + (size_t)2 * 64 * 64);
    // fused final gather (layer 2) + mean-pool accumulate
    k_gpool<<<3125, 256, 0, stream>>>((const uint4*)G0, A, cnt, ell, batch, pool, cntg);

    k_out<<<128, 256, 0, stream>>>(pool, cntg, W1, b1, out);
}